// Round 7
// baseline (430.054 us; speedup 1.0000x reference)
//
#include <hip/hip_runtime.h>
#include <hip/hip_bf16.h>
#include <cstdint>

#define S_LEN 2048
#define D_MOD 1024
#define N_HEADS 16
#define DK 64
#define D_FF 4096

typedef __bf16 bf16x8 __attribute__((ext_vector_type(8)));
typedef float f32x4 __attribute__((ext_vector_type(4)));

#define MFMA16(a, b, c) __builtin_amdgcn_mfma_f32_16x16x32_bf16((a), (b), (c), 0, 0, 0)

__device__ inline unsigned pack_bf16x2(float a, float b)
{
    unsigned short ua = __builtin_bit_cast(unsigned short, (__bf16)a);
    unsigned short ub = __builtin_bit_cast(unsigned short, (__bf16)b);
    return (unsigned)ua | ((unsigned)ub << 16);
}

__device__ inline float bf_bits_to_f32(unsigned us)
{
    return __builtin_bit_cast(float, us << 16);
}

// async global->LDS, 16B per lane; LDS dest must be wave-uniform-base + lane*16
__device__ inline void gload16(const void* g, void* l)
{
    __builtin_amdgcn_global_load_lds(
        (const __attribute__((address_space(1))) unsigned int*)g,
        (__attribute__((address_space(3))) unsigned int*)l, 16, 0, 0);
}

// ---------------------------------------------------------------------------
// Weight transpose + f32->bf16:  W[K][N] f32 -> WT[N][K] bf16
// ---------------------------------------------------------------------------
__global__ __launch_bounds__(256)
void transpose_f32_bf16(const float* __restrict__ W, __bf16* __restrict__ WT, int K, int N)
{
    __shared__ float tile[32][33];
    int tx = threadIdx.x & 31, ty = threadIdx.x >> 5;
    int n0 = blockIdx.x * 32, k0 = blockIdx.y * 32;
    for (int i = 0; i < 4; i++)
        tile[ty + i * 8][tx] = W[(size_t)(k0 + ty + i * 8) * N + n0 + tx];
    __syncthreads();
    for (int i = 0; i < 4; i++)
        WT[(size_t)(n0 + ty + i * 8) * K + k0 + tx] = (__bf16)tile[tx][ty + i * 8];
}

__global__ __launch_bounds__(256)
void convert_f32_bf16(const float* __restrict__ W, __bf16* __restrict__ o)
{
    int i = (blockIdx.x * 256 + threadIdx.x);
    float4 v = ((const float4*)W)[i];
    uint2 pk;
    pk.x = pack_bf16x2(v.x, v.y);
    pk.y = pack_bf16x2(v.z, v.w);
    ((uint2*)o)[i] = pk;
}

// ---------------------------------------------------------------------------
// bias matvecs, two-stage parallel reduce
// ---------------------------------------------------------------------------
__global__ __launch_bounds__(256)
void bias_stage1(const float* __restrict__ b_in, const float* __restrict__ bo,
                 const float* __restrict__ Wq, const float* __restrict__ Wk,
                 const float* __restrict__ Wv, const float* __restrict__ W2,
                 float* __restrict__ part)
{
    int n = blockIdx.x * 256 + threadIdx.x;
    int kc = blockIdx.y;
    int sel = n >> 10, col = n & 1023;
    const float* W = sel == 0 ? Wq : (sel == 1 ? Wk : (sel == 2 ? Wv : W2));
    const float* src = sel < 3 ? b_in : bo;
    float s = 0.f;
    for (int k = kc * 128; k < kc * 128 + 128; k++)
        s += src[k] * W[(size_t)k * 1024 + col];
    part[kc * 4096 + n] = s;
}

__global__ __launch_bounds__(256)
void bias_stage2(const float* __restrict__ part,
                 const float* __restrict__ bq, const float* __restrict__ bk,
                 const float* __restrict__ bv, const float* __restrict__ b2,
                 float* __restrict__ bqkv, float* __restrict__ bcomb)
{
    int n = blockIdx.x * 256 + threadIdx.x;
    int sel = n >> 10, col = n & 1023;
    float s = sel == 0 ? bq[col] : (sel == 1 ? bk[col] : (sel == 2 ? bv[col] : b2[col]));
    for (int kc = 0; kc < 8; kc++) s += part[kc * 4096 + n];
    if (n < 3072) bqkv[n] = s; else bcomb[col] = s;
}

// ---------------------------------------------------------------------------
// Per-head V transpose: qkv v-section [s][3072] -> VT[h][d][s] bf16
// ---------------------------------------------------------------------------
__global__ __launch_bounds__(256)
void vhead_transpose(const __bf16* __restrict__ v, __bf16* __restrict__ vt)
{
    __shared__ __bf16 tile[32][33];
    int tx = threadIdx.x & 31, ty = threadIdx.x >> 5;
    int s0 = blockIdx.x * 32;
    int d0 = blockIdx.y * 32;
    int h = blockIdx.z;
    for (int i = 0; i < 4; i++)
        tile[ty + i * 8][tx] = v[(size_t)(s0 + ty + i * 8) * 3072 + h * DK + d0 + tx];
    __syncthreads();
    for (int i = 0; i < 4; i++)
        vt[(size_t)(h * DK + d0 + ty + i * 8) * S_LEN + s0 + tx] = tile[tx][ty + i * 8];
}

// ---------------------------------------------------------------------------
// LayerNorm
// ---------------------------------------------------------------------------
__global__ __launch_bounds__(256)
void ln_kernel(const float* __restrict__ x, const float* __restrict__ gamma,
               const float* __restrict__ beta, __bf16* __restrict__ outb,
               float* __restrict__ outf)
{
    int row = blockIdx.x;
    int tid = threadIdx.x;
    const float4 v = ((const float4*)(x + (size_t)row * D_MOD))[tid];
    float s = v.x + v.y + v.z + v.w;
    float sq = v.x * v.x + v.y * v.y + v.z * v.z + v.w * v.w;
    for (int off = 32; off; off >>= 1) {
        s += __shfl_down(s, off);
        sq += __shfl_down(sq, off);
    }
    __shared__ float red[8];
    int wid = tid >> 6;
    if ((tid & 63) == 0) { red[wid] = s; red[wid + 4] = sq; }
    __syncthreads();
    s = red[0] + red[1] + red[2] + red[3];
    sq = red[4] + red[5] + red[6] + red[7];
    float mean = s * (1.f / D_MOD);
    float var = sq * (1.f / D_MOD) - mean * mean;
    var = fmaxf(var, 0.f);
    float inv = 1.f / (sqrtf(var) + 1e-6f);
    float4 gv = ((const float4*)gamma)[tid];
    float4 bv = ((const float4*)beta)[tid];
    float y0 = gv.x * ((v.x - mean) * inv) + bv.x;
    float y1 = gv.y * ((v.y - mean) * inv) + bv.y;
    float y2 = gv.z * ((v.z - mean) * inv) + bv.z;
    float y3 = gv.w * ((v.w - mean) * inv) + bv.w;
    uint2 pk;
    pk.x = pack_bf16x2(y0, y1);
    pk.y = pack_bf16x2(y2, y3);
    ((uint2*)(outb + (size_t)row * D_MOD))[tid] = pk;
    if (outf) {
        float4 o = {y0, y1, y2, y3};
        ((float4*)(outf + (size_t)row * D_MOD))[tid] = o;
    }
}

// ---------------------------------------------------------------------------
// GEMM: C[M][N] = A[M][K](bf16) * BT[N][K](bf16) + bias; 128xBN tile, BK=64
// ---------------------------------------------------------------------------
template<int BN, bool RELU, bool RES, bool WF32, bool WBF16>
__global__ __launch_bounds__(256, 2)
void gemm_kernel(const __bf16* __restrict__ A, const __bf16* __restrict__ BT,
                 const float* __restrict__ bias, const float* __restrict__ res,
                 float* __restrict__ Cf, __bf16* __restrict__ Cb,
                 int M, int N, int K)
{
    constexpr int NFRAG = BN / 32;
    __shared__ uint4 As[128 * 8];   // [row][8 x 16B] linear
    __shared__ uint4 Bs[BN * 8];
    const int tid = threadIdx.x;
    const int lane = tid & 63;
    const int w = tid >> 6;
    const int lrow = lane & 15;
    const int g = lane >> 4;
    const int bm = blockIdx.y * 128;
    const int bn = blockIdx.x * BN;
    const int wrow = (w >> 1) * 64;
    const int wcol = (w & 1) * (BN / 2);

    f32x4 acc[4][NFRAG];
    for (int m = 0; m < 4; m++)
        for (int n = 0; n < NFRAG; n++)
            acc[m][n] = (f32x4){0.f, 0.f, 0.f, 0.f};

    const int srow = tid >> 3;   // 0..31
    const int sc = tid & 7;      // 16B chunk
    const __bf16* Ag = A + (size_t)(bm + srow) * K + sc * 8;
    const __bf16* Bg = BT + (size_t)(bn + srow) * K + sc * 8;

    for (int kt = 0; kt < K; kt += 64) {
        __syncthreads();   // previous iteration's LDS reads complete
        #pragma unroll
        for (int p = 0; p < 4; p++)
            gload16(Ag + (size_t)(p * 32) * K + kt, &As[(srow + p * 32) * 8 + sc]);
        #pragma unroll
        for (int p = 0; p < NFRAG; p++)
            gload16(Bg + (size_t)(p * 32) * K + kt, &Bs[(srow + p * 32) * 8 + sc]);
        asm volatile("s_waitcnt vmcnt(0)" ::: "memory");
        __syncthreads();
        #pragma unroll
        for (int kk = 0; kk < 2; kk++) {
            bf16x8 af[4], bfr[NFRAG];
            int c = kk * 4 + g;
            #pragma unroll
            for (int m = 0; m < 4; m++)
                af[m] = __builtin_bit_cast(bf16x8, As[(wrow + m * 16 + lrow) * 8 + c]);
            #pragma unroll
            for (int n = 0; n < NFRAG; n++)
                bfr[n] = __builtin_bit_cast(bf16x8, Bs[(wcol + n * 16 + lrow) * 8 + c]);
            #pragma unroll
            for (int m = 0; m < 4; m++)
                #pragma unroll
                for (int n = 0; n < NFRAG; n++)
                    acc[m][n] = MFMA16(af[m], bfr[n], acc[m][n]);
        }
    }

    for (int n = 0; n < NFRAG; n++) {
        int col = bn + wcol + n * 16 + lrow;
        float bval = bias ? bias[col] : 0.f;
        for (int m = 0; m < 4; m++) {
            int row0 = bm + wrow + m * 16 + g * 4;
            for (int r = 0; r < 4; r++) {
                int row = row0 + r;
                float v = acc[m][n][r] + bval;
                if (RELU) v = fmaxf(v, 0.f);
                if (RES) v += res[(size_t)row * N + col];
                if (WF32) Cf[(size_t)row * N + col] = v;
                if (WBF16) Cb[(size_t)row * N + col] = (__bf16)v;
            }
        }
    }
}

// ---------------------------------------------------------------------------
// attn_fused v4: block = (16-row band, head), 512 threads = 8 waves.
// Waves split kv tiles 8-way. Pass A: partial (m,l) -> LDS combine.
// Pass B: QK^T -> P (bf16 LDS stage -> coalesced f32 copy-out) + partial PV.
// PV partials combined via LDS float[16][64] per wave.
// ---------------------------------------------------------------------------
__global__ __launch_bounds__(512)
void attn_fused(const __bf16* __restrict__ qkv, const __bf16* __restrict__ vt,
                float* __restrict__ P, __bf16* __restrict__ ctx)
{
    __shared__ char Plds[8][4096];          // per-wave P stage; then f32 reduce buf
    __shared__ float cmw[8][16], clw[8][16];
    const int tid = threadIdx.x;
    const int lane = tid & 63;
    const int w = tid >> 6;                   // 0..7
    const int lrow = lane & 15;
    const int g = lane >> 4;
    const int band = 127 - (int)blockIdx.x;   // heavy first
    const int h = blockIdx.y;
    const int qg = band * 16 + lrow;          // this lane's q row
    const int ntiles = band / 8 + 1;          // causal 128-wide kv tiles
    const float c1 = 0.18033688f;             // 0.125 * log2(e)

    const __bf16* ksec = qkv + 1024;
    const size_t Pb = (size_t)h * S_LEN * S_LEN;
    char* plB = Plds[w];

    bf16x8 qf[2];
    qf[0] = *(const bf16x8*)(qkv + (size_t)qg * 3072 + h * DK + g * 8);
    qf[1] = *(const bf16x8*)(qkv + (size_t)qg * 3072 + h * DK + 32 + g * 8);

    // ---- pass A: partial row max m2 (base-2 domain) and sum l over my tiles ----
    float m2 = -1e30f, l = 0.f;
    for (int kt = w; kt < ntiles; kt += 8) {
        f32x4 acc[8];
        #pragma unroll
        for (int mf = 0; mf < 8; mf++) acc[mf] = (f32x4){0.f, 0.f, 0.f, 0.f};
        const __bf16* kbase = ksec + (size_t)(kt * 128 + lrow) * 3072 + h * DK + g * 8;
        #pragma unroll
        for (int kk = 0; kk < 2; kk++)
            #pragma unroll
            for (int mf = 0; mf < 8; mf++) {
                bf16x8 kf = *(const bf16x8*)(kbase + (size_t)(mf * 16) * 3072 + kk * 32);
                acc[mf] = MFMA16(kf, qf[kk], acc[mf]);
            }
        float s[8][4];
        float mx[8];
        #pragma unroll
        for (int mf = 0; mf < 8; mf++) {
            int kvb = kt * 128 + mf * 16 + g * 4;
            #pragma unroll
            for (int r = 0; r < 4; r++)
                s[mf][r] = (kvb + r <= qg) ? acc[mf][r] * c1 : -1e30f;
            mx[mf] = fmaxf(fmaxf(s[mf][0], s[mf][1]), fmaxf(s[mf][2], s[mf][3]));
        }
        float tm = fmaxf(fmaxf(fmaxf(mx[0], mx[1]), fmaxf(mx[2], mx[3])),
                         fmaxf(fmaxf(mx[4], mx[5]), fmaxf(mx[6], mx[7])));
        float nm = fmaxf(m2, tm);
        float sum = 0.f;
        #pragma unroll
        for (int mf = 0; mf < 8; mf++) {
            float e0 = exp2f(s[mf][0] - nm), e1 = exp2f(s[mf][1] - nm);
            float e2 = exp2f(s[mf][2] - nm), e3 = exp2f(s[mf][3] - nm);
            sum += (e0 + e1) + (e2 + e3);
        }
        l = l * exp2f(m2 - nm) + sum;
        m2 = nm;
    }
    // combine across the 4 g-groups (lanes sharing lrow)
    #pragma unroll
    for (int off = 16; off <= 32; off <<= 1) {
        float om = __shfl_xor(m2, off);
        float ol = __shfl_xor(l, off);
        float nm = fmaxf(m2, om);
        l = l * exp2f(m2 - nm) + ol * exp2f(om - nm);
        m2 = nm;
    }
    if (lane < 16) { cmw[w][lrow] = m2; clw[w][lrow] = l; }
    __syncthreads();
    // combine across 8 waves
    {
        float M = cmw[0][lrow];
        #pragma unroll
        for (int i = 1; i < 8; i++) M = fmaxf(M, cmw[i][lrow]);
        float L = 0.f;
        #pragma unroll
        for (int i = 0; i < 8; i++) L += clw[i][lrow] * exp2f(cmw[i][lrow] - M);
        m2 = M; l = L;
    }
    const float offv = -m2 - log2f(l);

    // ---- pass B: normalized P + partial PV over my tiles ----
    f32x4 acc2[4];
    #pragma unroll
    for (int i = 0; i < 4; i++) acc2[i] = (f32x4){0.f, 0.f, 0.f, 0.f};

    for (int kt = w; kt < ntiles; kt += 8) {
        f32x4 acc[8];
        #pragma unroll
        for (int mf = 0; mf < 8; mf++) acc[mf] = (f32x4){0.f, 0.f, 0.f, 0.f};
        const __bf16* kbase = ksec + (size_t)(kt * 128 + lrow) * 3072 + h * DK + g * 8;
        #pragma unroll
        for (int kk = 0; kk < 2; kk++)
            #pragma unroll
            for (int mf = 0; mf < 8; mf++) {
                bf16x8 kf = *(const bf16x8*)(kbase + (size_t)(mf * 16) * 3072 + kk * 32);
                acc[mf] = MFMA16(kf, qf[kk], acc[mf]);
            }
        #pragma unroll
        for (int mf = 0; mf < 8; mf++) {
            int kvb = kt * 128 + mf * 16 + g * 4;
            float p0 = (kvb + 0 <= qg) ? exp2f(acc[mf][0] * c1 + offv) : 0.f;
            float p1 = (kvb + 1 <= qg) ? exp2f(acc[mf][1] * c1 + offv) : 0.f;
            float p2 = (kvb + 2 <= qg) ? exp2f(acc[mf][2] * c1 + offv) : 0.f;
            float p3 = (kvb + 3 <= qg) ? exp2f(acc[mf][3] * c1 + offv) : 0.f;
            uint2 pk;
            pk.x = pack_bf16x2(p0, p1);
            pk.y = pack_bf16x2(p2, p3);
            *(uint2*)(plB + ((lrow * 256 + mf * 32 + g * 8) ^ ((lrow & 7) << 4))) = pk;
        }
        // PV on this tile
        #pragma unroll
        for (int ks = 0; ks < 4; ks++) {
            bf16x8 pf = *(bf16x8*)(plB + ((lrow * 256 + ks * 64 + g * 16) ^ ((lrow & 7) << 4)));
            const __bf16* vp = vt + (size_t)(h * DK + lrow) * S_LEN + kt * 128 + ks * 32 + g * 8;
            #pragma unroll
            for (int md = 0; md < 4; md++) {
                bf16x8 vf = *(const bf16x8*)(vp + (size_t)(md * 16) * S_LEN);
                acc2[md] = MFMA16(vf, pf, acc2[md]);
            }
        }
        // coalesced copy-out: P tile f32 from bf16 LDS stage
        {
            const int r2 = lane >> 5;      // 0..1
            const int cb = lane & 31;      // 8B units within a row
            #pragma unroll
            for (int it = 0; it < 8; it++) {
                int r = it * 2 + r2;
                uint2 pk = *(uint2*)(plB + ((r * 256 + cb * 8) ^ ((r & 7) << 4)));
                f32x4 v;
                v[0] = bf_bits_to_f32(pk.x & 0xffffu);
                v[1] = bf_bits_to_f32(pk.x >> 16);
                v[2] = bf_bits_to_f32(pk.y & 0xffffu);
                v[3] = bf_bits_to_f32(pk.y >> 16);
                *(f32x4*)(P + Pb + (size_t)(band * 16 + r) * S_LEN + kt * 128 + cb * 4) = v;
            }
        }
    }

    // ---- cross-wave PV reduce: each wave dumps rv[q][d] = float[16][64] ----
    __syncthreads();   // all P copy-outs done before overwriting stage buffers
    {
        float* rv = (float*)plB;
        #pragma unroll
        for (int md = 0; md < 4; md++)
            #pragma unroll
            for (int r = 0; r < 4; r++)
                rv[lrow * 64 + md * 16 + g * 4 + r] = acc2[md][r];
    }
    __syncthreads();
    {
        // thread t handles ctx elems 2t, 2t+1: q = t>>5, d = (t&31)*2
        int q = tid >> 5;
        int d = (tid & 31) * 2;
        int idx = q * 64 + d;
        float v0 = 0.f, v1 = 0.f;
        #pragma unroll
        for (int i = 0; i < 8; i++) {
            const float* rv = (const float*)Plds[i];
            v0 += rv[idx];
            v1 += rv[idx + 1];
        }
        unsigned pk = pack_bf16x2(v0, v1);
        *(unsigned*)(ctx + (size_t)(band * 16 + q) * D_MOD + h * DK + d) = pk;
    }

    // ---- zero-fill masked tail columns; wave w covers rows 2w, 2w+1 ----
    const int z0 = ntiles * 128;
    if (z0 < S_LEN) {
        f32x4 z = {0.f, 0.f, 0.f, 0.f};
        #pragma unroll
        for (int rr = w * 2; rr < w * 2 + 2; rr++) {
            float* rowp = P + Pb + (size_t)(band * 16 + rr) * S_LEN;
            for (int c = z0 + lane * 4; c < S_LEN; c += 256)
                *(f32x4*)(rowp + c) = z;
        }
    }
}

// ---------------------------------------------------------------------------
extern "C" void kernel_launch(void* const* d_in, const int* in_sizes, int n_in,
                              void* d_out, int out_size, void* d_ws, size_t ws_size,
                              hipStream_t stream)
{
    const float* x     = (const float*)d_in[0];
    const float* g1    = (const float*)d_in[1];
    const float* beta1 = (const float*)d_in[2];
    const float* W_in  = (const float*)d_in[3];
    const float* b_in  = (const float*)d_in[4];
    const float* Wq    = (const float*)d_in[5];
    const float* bq    = (const float*)d_in[6];
    const float* Wk    = (const float*)d_in[7];
    const float* bk    = (const float*)d_in[8];
    const float* Wv    = (const float*)d_in[9];
    const float* bv    = (const float*)d_in[10];
    const float* Wo    = (const float*)d_in[11];
    const float* bo    = (const float*)d_in[12];
    const float* W2    = (const float*)d_in[13];
    const float* b2    = (const float*)d_in[14];
    const float* g2    = (const float*)d_in[15];
    const float* beta2 = (const float*)d_in[16];
    const float* Wf1   = (const float*)d_in[17];
    const float* bf1   = (const float*)d_in[18];
    const float* Wf2   = (const float*)d_in[19];
    const float* bf2   = (const float*)d_in[20];

    float* outp = (float*)d_out;                    // [2048][1024]
    float* Pout = outp + (size_t)S_LEN * D_MOD;     // [16][2048][2048]

    char* p = (char*)d_ws;
    auto alloc = [&](size_t b) -> void* {
        void* r = (void*)p;
        p += (b + 255) & ~(size_t)255;
        return r;
    };
    __bf16* WqkvT    = (__bf16*)alloc((size_t)3072 * 1024 * 2);
    __bf16* W2T      = (__bf16*)alloc((size_t)1024 * 1024 * 2);
    __bf16* Wf1T     = (__bf16*)alloc((size_t)D_FF * D_MOD * 2);
    __bf16* Wf2T     = (__bf16*)alloc((size_t)D_MOD * D_FF * 2);
    __bf16* WqkvCT   = (__bf16*)alloc((size_t)3072 * 1024 * 2);
    __bf16* WcombT   = (__bf16*)alloc((size_t)1024 * 1024 * 2);
    float*  bqkv     = (float*)alloc((size_t)3072 * 4);
    float*  bcomb    = (float*)alloc((size_t)1024 * 4);
    float*  biaspart = (float*)alloc((size_t)8 * 4096 * 4);
    __bf16* xn_b     = (__bf16*)alloc((size_t)S_LEN * D_MOD * 2);
    __bf16* qkv_b    = (__bf16*)alloc((size_t)S_LEN * 3072 * 2);
    __bf16* VT       = (__bf16*)alloc((size_t)N_HEADS * DK * S_LEN * 2);
    __bf16* ctx_b    = (__bf16*)alloc((size_t)S_LEN * D_MOD * 2);
    float*  part1f   = (float*)alloc((size_t)S_LEN * D_MOD * 4);
    float*  norm2f   = (float*)alloc((size_t)S_LEN * D_MOD * 4);
    __bf16* norm2b   = (__bf16*)alloc((size_t)S_LEN * D_MOD * 2);
    __bf16* ff1_b    = (__bf16*)alloc((size_t)S_LEN * D_FF * 2);
    // aliases: weight staging only needed before part1f/norm2f are written
    __bf16* Win_b = (__bf16*)part1f;
    __bf16* Wo_b  = (__bf16*)norm2f;

    dim3 blk(256);
    dim3 blk512(512);

    // --- weight prep ---
    transpose_f32_bf16<<<dim3(32, 32), blk, 0, stream>>>(Wq, WqkvT, 1024, 1024);
    transpose_f32_bf16<<<dim3(32, 32), blk, 0, stream>>>(Wk, WqkvT + 1024 * 1024, 1024, 1024);
    transpose_f32_bf16<<<dim3(32, 32), blk, 0, stream>>>(Wv, WqkvT + 2 * 1024 * 1024, 1024, 1024);
    transpose_f32_bf16<<<dim3(32, 32), blk, 0, stream>>>(W2, W2T, 1024, 1024);
    transpose_f32_bf16<<<dim3(128, 32), blk, 0, stream>>>(Wf1, Wf1T, 1024, 4096);
    transpose_f32_bf16<<<dim3(32, 128), blk, 0, stream>>>(Wf2, Wf2T, 4096, 1024);
    convert_f32_bf16<<<dim3(1024), blk, 0, stream>>>(W_in, Win_b);
    convert_f32_bf16<<<dim3(1024), blk, 0, stream>>>(Wo, Wo_b);
    bias_stage1<<<dim3(16, 8), blk, 0, stream>>>(b_in, bo, Wq, Wk, Wv, W2, biaspart);
    bias_stage2<<<dim3(16), blk, 0, stream>>>(biaspart, bq, bk, bv, b2, bqkv, bcomb);

    // (Win·Wqkv)^T and (Wo·W2)^T
    gemm_kernel<64, false, false, false, true><<<dim3(16, 24), blk, 0, stream>>>(
        WqkvT, Win_b, nullptr, nullptr, nullptr, WqkvCT, 3072, 1024, 1024);
    gemm_kernel<64, false, false, false, true><<<dim3(16, 8), blk, 0, stream>>>(
        W2T, Wo_b, nullptr, nullptr, nullptr, WcombT, 1024, 1024, 1024);

    // --- forward ---
    ln_kernel<<<S_LEN, blk, 0, stream>>>(x, g1, beta1, xn_b, nullptr);

    gemm_kernel<128, false, false, false, true><<<dim3(24, 16), blk, 0, stream>>>(
        xn_b, WqkvCT, bqkv, nullptr, nullptr, qkv_b, 2048, 3072, 1024);

    vhead_transpose<<<dim3(64, 2, 16), blk, 0, stream>>>(qkv_b + 2048, VT);

    attn_fused<<<dim3(128, 16), blk512, 0, stream>>>(qkv_b, VT, Pout, ctx_b);

    gemm_kernel<64, false, true, true, false><<<dim3(16, 16), blk, 0, stream>>>(
        ctx_b, WcombT, bcomb, x, part1f, nullptr, 2048, 1024, 1024);

    ln_kernel<<<S_LEN, blk, 0, stream>>>(part1f, g2, beta2, norm2b, norm2f);

    gemm_kernel<128, true, false, false, true><<<dim3(32, 16), blk, 0, stream>>>(
        norm2b, Wf1T, bf1, nullptr, nullptr, ff1_b, 2048, 4096, 1024);

    gemm_kernel<64, false, true, true, false><<<dim3(16, 16), blk, 0, stream>>>(
        ff1_b, Wf2T, bf2, norm2f, outp, nullptr, 2048, 1024, 4096);
}

// Round 8
// 414.623 us; speedup vs baseline: 1.0372x; 1.0372x over previous
//
#include <hip/hip_runtime.h>
#include <hip/hip_bf16.h>
#include <cstdint>

#define S_LEN 2048
#define D_MOD 1024
#define N_HEADS 16
#define DK 64
#define D_FF 4096

typedef __bf16 bf16x8 __attribute__((ext_vector_type(8)));
typedef float f32x4 __attribute__((ext_vector_type(4)));

#define MFMA16(a, b, c) __builtin_amdgcn_mfma_f32_16x16x32_bf16((a), (b), (c), 0, 0, 0)

__device__ inline unsigned pack_bf16x2(float a, float b)
{
    unsigned short ua = __builtin_bit_cast(unsigned short, (__bf16)a);
    unsigned short ub = __builtin_bit_cast(unsigned short, (__bf16)b);
    return (unsigned)ua | ((unsigned)ub << 16);
}

// async global->LDS, 16B per lane; LDS dest must be wave-uniform-base + lane*16
__device__ inline void gload16(const void* g, void* l)
{
    __builtin_amdgcn_global_load_lds(
        (const __attribute__((address_space(1))) unsigned int*)g,
        (__attribute__((address_space(3))) unsigned int*)l, 16, 0, 0);
}

// ---------------------------------------------------------------------------
// Weight transpose + f32->bf16:  W[K][N] f32 -> WT[N][K] bf16
// ---------------------------------------------------------------------------
__global__ __launch_bounds__(256)
void transpose_f32_bf16(const float* __restrict__ W, __bf16* __restrict__ WT, int K, int N)
{
    __shared__ float tile[32][33];
    int tx = threadIdx.x & 31, ty = threadIdx.x >> 5;
    int n0 = blockIdx.x * 32, k0 = blockIdx.y * 32;
    for (int i = 0; i < 4; i++)
        tile[ty + i * 8][tx] = W[(size_t)(k0 + ty + i * 8) * N + n0 + tx];
    __syncthreads();
    for (int i = 0; i < 4; i++)
        WT[(size_t)(n0 + ty + i * 8) * K + k0 + tx] = (__bf16)tile[tx][ty + i * 8];
}

__global__ __launch_bounds__(256)
void convert_f32_bf16(const float* __restrict__ W, __bf16* __restrict__ o)
{
    int i = (blockIdx.x * 256 + threadIdx.x);
    float4 v = ((const float4*)W)[i];
    uint2 pk;
    pk.x = pack_bf16x2(v.x, v.y);
    pk.y = pack_bf16x2(v.z, v.w);
    ((uint2*)o)[i] = pk;
}

// ---------------------------------------------------------------------------
// bias matvecs, two-stage parallel reduce
// ---------------------------------------------------------------------------
__global__ __launch_bounds__(256)
void bias_stage1(const float* __restrict__ b_in, const float* __restrict__ bo,
                 const float* __restrict__ Wq, const float* __restrict__ Wk,
                 const float* __restrict__ Wv, const float* __restrict__ W2,
                 float* __restrict__ part)
{
    int n = blockIdx.x * 256 + threadIdx.x;
    int kc = blockIdx.y;
    int sel = n >> 10, col = n & 1023;
    const float* W = sel == 0 ? Wq : (sel == 1 ? Wk : (sel == 2 ? Wv : W2));
    const float* src = sel < 3 ? b_in : bo;
    float s = 0.f;
    for (int k = kc * 128; k < kc * 128 + 128; k++)
        s += src[k] * W[(size_t)k * 1024 + col];
    part[kc * 4096 + n] = s;
}

__global__ __launch_bounds__(256)
void bias_stage2(const float* __restrict__ part,
                 const float* __restrict__ bq, const float* __restrict__ bk,
                 const float* __restrict__ bv, const float* __restrict__ b2,
                 float* __restrict__ bqkv, float* __restrict__ bcomb)
{
    int n = blockIdx.x * 256 + threadIdx.x;
    int sel = n >> 10, col = n & 1023;
    float s = sel == 0 ? bq[col] : (sel == 1 ? bk[col] : (sel == 2 ? bv[col] : b2[col]));
    for (int kc = 0; kc < 8; kc++) s += part[kc * 4096 + n];
    if (n < 3072) bqkv[n] = s; else bcomb[col] = s;
}

// ---------------------------------------------------------------------------
// Per-head V transpose: qkv v-section [s][3072] -> VT[h][d][s] bf16
// ---------------------------------------------------------------------------
__global__ __launch_bounds__(256)
void vhead_transpose(const __bf16* __restrict__ v, __bf16* __restrict__ vt)
{
    __shared__ __bf16 tile[32][33];
    int tx = threadIdx.x & 31, ty = threadIdx.x >> 5;
    int s0 = blockIdx.x * 32;
    int d0 = blockIdx.y * 32;
    int h = blockIdx.z;
    for (int i = 0; i < 4; i++)
        tile[ty + i * 8][tx] = v[(size_t)(s0 + ty + i * 8) * 3072 + h * DK + d0 + tx];
    __syncthreads();
    for (int i = 0; i < 4; i++)
        vt[(size_t)(h * DK + d0 + ty + i * 8) * S_LEN + s0 + tx] = tile[tx][ty + i * 8];
}

// ---------------------------------------------------------------------------
// LayerNorm
// ---------------------------------------------------------------------------
__global__ __launch_bounds__(256)
void ln_kernel(const float* __restrict__ x, const float* __restrict__ gamma,
               const float* __restrict__ beta, __bf16* __restrict__ outb,
               float* __restrict__ outf)
{
    int row = blockIdx.x;
    int tid = threadIdx.x;
    const float4 v = ((const float4*)(x + (size_t)row * D_MOD))[tid];
    float s = v.x + v.y + v.z + v.w;
    float sq = v.x * v.x + v.y * v.y + v.z * v.z + v.w * v.w;
    for (int off = 32; off; off >>= 1) {
        s += __shfl_down(s, off);
        sq += __shfl_down(sq, off);
    }
    __shared__ float red[8];
    int wid = tid >> 6;
    if ((tid & 63) == 0) { red[wid] = s; red[wid + 4] = sq; }
    __syncthreads();
    s = red[0] + red[1] + red[2] + red[3];
    sq = red[4] + red[5] + red[6] + red[7];
    float mean = s * (1.f / D_MOD);
    float var = sq * (1.f / D_MOD) - mean * mean;
    var = fmaxf(var, 0.f);
    float inv = 1.f / (sqrtf(var) + 1e-6f);
    float4 gv = ((const float4*)gamma)[tid];
    float4 bv = ((const float4*)beta)[tid];
    float y0 = gv.x * ((v.x - mean) * inv) + bv.x;
    float y1 = gv.y * ((v.y - mean) * inv) + bv.y;
    float y2 = gv.z * ((v.z - mean) * inv) + bv.z;
    float y3 = gv.w * ((v.w - mean) * inv) + bv.w;
    uint2 pk;
    pk.x = pack_bf16x2(y0, y1);
    pk.y = pack_bf16x2(y2, y3);
    ((uint2*)(outb + (size_t)row * D_MOD))[tid] = pk;
    if (outf) {
        float4 o = {y0, y1, y2, y3};
        ((float4*)(outf + (size_t)row * D_MOD))[tid] = o;
    }
}

// ---------------------------------------------------------------------------
// GEMM: C[M][N] = A[M][K](bf16) * BT[N][K](bf16) + bias; 128xBN tile, BK=64
// ---------------------------------------------------------------------------
template<int BN, bool RELU, bool RES, bool WF32, bool WBF16>
__global__ __launch_bounds__(256, 2)
void gemm_kernel(const __bf16* __restrict__ A, const __bf16* __restrict__ BT,
                 const float* __restrict__ bias, const float* __restrict__ res,
                 float* __restrict__ Cf, __bf16* __restrict__ Cb,
                 int M, int N, int K)
{
    constexpr int NFRAG = BN / 32;
    __shared__ uint4 As[128 * 8];   // [row][8 x 16B] linear
    __shared__ uint4 Bs[BN * 8];
    const int tid = threadIdx.x;
    const int lane = tid & 63;
    const int w = tid >> 6;
    const int lrow = lane & 15;
    const int g = lane >> 4;
    const int bm = blockIdx.y * 128;
    const int bn = blockIdx.x * BN;
    const int wrow = (w >> 1) * 64;
    const int wcol = (w & 1) * (BN / 2);

    f32x4 acc[4][NFRAG];
    for (int m = 0; m < 4; m++)
        for (int n = 0; n < NFRAG; n++)
            acc[m][n] = (f32x4){0.f, 0.f, 0.f, 0.f};

    const int srow = tid >> 3;   // 0..31
    const int sc = tid & 7;      // 16B chunk
    const __bf16* Ag = A + (size_t)(bm + srow) * K + sc * 8;
    const __bf16* Bg = BT + (size_t)(bn + srow) * K + sc * 8;

    for (int kt = 0; kt < K; kt += 64) {
        __syncthreads();   // previous iteration's LDS reads complete
        #pragma unroll
        for (int p = 0; p < 4; p++)
            gload16(Ag + (size_t)(p * 32) * K + kt, &As[(srow + p * 32) * 8 + sc]);
        #pragma unroll
        for (int p = 0; p < NFRAG; p++)
            gload16(Bg + (size_t)(p * 32) * K + kt, &Bs[(srow + p * 32) * 8 + sc]);
        asm volatile("s_waitcnt vmcnt(0)" ::: "memory");
        __syncthreads();
        #pragma unroll
        for (int kk = 0; kk < 2; kk++) {
            bf16x8 af[4], bfr[NFRAG];
            int c = kk * 4 + g;
            #pragma unroll
            for (int m = 0; m < 4; m++)
                af[m] = __builtin_bit_cast(bf16x8, As[(wrow + m * 16 + lrow) * 8 + c]);
            #pragma unroll
            for (int n = 0; n < NFRAG; n++)
                bfr[n] = __builtin_bit_cast(bf16x8, Bs[(wcol + n * 16 + lrow) * 8 + c]);
            #pragma unroll
            for (int m = 0; m < 4; m++)
                #pragma unroll
                for (int n = 0; n < NFRAG; n++)
                    acc[m][n] = MFMA16(af[m], bfr[n], acc[m][n]);
        }
    }

    for (int n = 0; n < NFRAG; n++) {
        int col = bn + wcol + n * 16 + lrow;
        float bval = bias ? bias[col] : 0.f;
        for (int m = 0; m < 4; m++) {
            int row0 = bm + wrow + m * 16 + g * 4;
            for (int r = 0; r < 4; r++) {
                int row = row0 + r;
                float v = acc[m][n][r] + bval;
                if (RELU) v = fmaxf(v, 0.f);
                if (RES) v += res[(size_t)row * N + col];
                if (WF32) Cf[(size_t)row * N + col] = v;
                if (WBF16) Cb[(size_t)row * N + col] = (__bf16)v;
            }
        }
    }
}

// ---------------------------------------------------------------------------
// attn_flash: single-pass online-softmax flash attention (no P write).
// Block = (16-row band, head), 4 waves split kv tiles. Outputs ctx (bf16)
// and Obuf[h][q] = -M - log2(L) for the P-writer kernel.
// ---------------------------------------------------------------------------
__global__ __launch_bounds__(256)
void attn_flash(const __bf16* __restrict__ qkv, const __bf16* __restrict__ vt,
                float* __restrict__ Obuf, __bf16* __restrict__ ctx)
{
    __shared__ char Plds[4][4096];          // per-wave P stage; then f32 reduce buf
    __shared__ float cmw[4][16], clw[4][16], Linv[16];
    const int tid = threadIdx.x;
    const int lane = tid & 63;
    const int w = tid >> 6;
    const int lrow = lane & 15;
    const int g = lane >> 4;
    const int band = 127 - (int)blockIdx.x;   // heavy first
    const int h = blockIdx.y;
    const int qg = band * 16 + lrow;          // this lane's q row
    const int ntiles = band / 8 + 1;          // causal 128-wide kv tiles
    const float c1 = 0.18033688f;             // 0.125 * log2(e)

    const __bf16* ksec = qkv + 1024;
    char* plB = Plds[w];

    bf16x8 qf[2];
    qf[0] = *(const bf16x8*)(qkv + (size_t)qg * 3072 + h * DK + g * 8);
    qf[1] = *(const bf16x8*)(qkv + (size_t)qg * 3072 + h * DK + 32 + g * 8);

    float m2 = -1e30f, l = 0.f;
    f32x4 acc2[4];
    #pragma unroll
    for (int i = 0; i < 4; i++) acc2[i] = (f32x4){0.f, 0.f, 0.f, 0.f};

    for (int kt = w; kt < ntiles; kt += 4) {
        f32x4 acc[8];
        #pragma unroll
        for (int mf = 0; mf < 8; mf++) acc[mf] = (f32x4){0.f, 0.f, 0.f, 0.f};
        const __bf16* kbase = ksec + (size_t)(kt * 128 + lrow) * 3072 + h * DK + g * 8;
        #pragma unroll
        for (int kk = 0; kk < 2; kk++)
            #pragma unroll
            for (int mf = 0; mf < 8; mf++) {
                bf16x8 kf = *(const bf16x8*)(kbase + (size_t)(mf * 16) * 3072 + kk * 32);
                acc[mf] = MFMA16(kf, qf[kk], acc[mf]);
            }
        // masked scores (base-2 domain) + tile row-max
        float s[8][4], mx[8];
        #pragma unroll
        for (int mf = 0; mf < 8; mf++) {
            int kvb = kt * 128 + mf * 16 + g * 4;
            #pragma unroll
            for (int r = 0; r < 4; r++)
                s[mf][r] = (kvb + r <= qg) ? acc[mf][r] * c1 : -1e30f;
            mx[mf] = fmaxf(fmaxf(s[mf][0], s[mf][1]), fmaxf(s[mf][2], s[mf][3]));
        }
        float tm = fmaxf(fmaxf(fmaxf(mx[0], mx[1]), fmaxf(mx[2], mx[3])),
                         fmaxf(fmaxf(mx[4], mx[5]), fmaxf(mx[6], mx[7])));
        tm = fmaxf(tm, __shfl_xor(tm, 16));
        tm = fmaxf(tm, __shfl_xor(tm, 32));      // row max across g groups
        float nm = fmaxf(m2, tm);
        float scale = exp2f(m2 - nm);
        m2 = nm;
        // p = exp2(s - m), stage bf16, accumulate l
        float sum = 0.f;
        #pragma unroll
        for (int mf = 0; mf < 8; mf++) {
            float p0 = exp2f(s[mf][0] - nm);
            float p1 = exp2f(s[mf][1] - nm);
            float p2 = exp2f(s[mf][2] - nm);
            float p3 = exp2f(s[mf][3] - nm);
            sum += (p0 + p1) + (p2 + p3);
            uint2 pk;
            pk.x = pack_bf16x2(p0, p1);
            pk.y = pack_bf16x2(p2, p3);
            *(uint2*)(plB + ((lrow * 256 + mf * 32 + g * 8) ^ ((lrow & 7) << 4))) = pk;
        }
        l = l * scale + sum;
        #pragma unroll
        for (int md = 0; md < 4; md++) acc2[md] *= scale;
        // PV on this tile
        #pragma unroll
        for (int ks = 0; ks < 4; ks++) {
            bf16x8 pf = *(bf16x8*)(plB + ((lrow * 256 + ks * 64 + g * 16) ^ ((lrow & 7) << 4)));
            const __bf16* vp = vt + (size_t)(h * DK + lrow) * S_LEN + kt * 128 + ks * 32 + g * 8;
            #pragma unroll
            for (int md = 0; md < 4; md++) {
                bf16x8 vf = *(const bf16x8*)(vp + (size_t)(md * 16) * S_LEN);
                acc2[md] = MFMA16(vf, pf, acc2[md]);
            }
        }
    }

    // cross-g l sum (m2 already uniform per lrow after per-tile max combine)
    l += __shfl_xor(l, 16);
    l += __shfl_xor(l, 32);
    if (lane < 16) { cmw[w][lrow] = m2; clw[w][lrow] = l; }
    __syncthreads();
    float M = fmaxf(fmaxf(cmw[0][lrow], cmw[1][lrow]), fmaxf(cmw[2][lrow], cmw[3][lrow]));
    float L = clw[0][lrow] * exp2f(cmw[0][lrow] - M)
            + clw[1][lrow] * exp2f(cmw[1][lrow] - M)
            + clw[2][lrow] * exp2f(cmw[2][lrow] - M)
            + clw[3][lrow] * exp2f(cmw[3][lrow] - M);
    // dump scaled acc2 into own stage buffer (swizzled rows of [16 q][64 d])
    {
        float sw = exp2f(m2 - M);
        float* rv = (float*)plB;
        #pragma unroll
        for (int md = 0; md < 4; md++) {
            int off = (md * 16 + g * 4) ^ ((lrow & 7) << 3);
            f32x4 t = acc2[md] * sw;
            *(f32x4*)(rv + lrow * 64 + off) = t;
        }
    }
    if (w == 0 && lane < 16) {
        Obuf[h * S_LEN + qg] = -M - log2f(L);
        Linv[lrow] = 1.f / L;
    }
    __syncthreads();
    // final combine: thread handles (q = tid>>4, d0 = (tid&15)*4)
    {
        int q = tid >> 4, d0 = (tid & 15) * 4;
        int off = q * 64 + (d0 ^ ((q & 7) << 3));
        f32x4 v = *(const f32x4*)((const float*)Plds[0] + off);
        v += *(const f32x4*)((const float*)Plds[1] + off);
        v += *(const f32x4*)((const float*)Plds[2] + off);
        v += *(const f32x4*)((const float*)Plds[3] + off);
        float li = Linv[q];
        uint2 pk;
        pk.x = pack_bf16x2(v[0] * li, v[1] * li);
        pk.y = pack_bf16x2(v[2] * li, v[3] * li);
        *(uint2*)(ctx + (size_t)(band * 16 + q) * D_MOD + h * DK + d0) = pk;
    }
}

// ---------------------------------------------------------------------------
// attn_pwrite: streaming P materialization. Block = 128x128 tile (kt,qt,h).
// kt>qt: pure zero-fill. Else: direct-global Q/K frags, swapped mfma(K,Q),
// epilogue exp2 with Obuf, contiguous f32x4 stores. No LDS, no barriers.
// ---------------------------------------------------------------------------
__global__ __launch_bounds__(256)
void attn_pwrite(const __bf16* __restrict__ qkv, const float* __restrict__ Obuf,
                 float* __restrict__ P)
{
    const int kt = blockIdx.x, qt = blockIdx.y, h = blockIdx.z;
    const size_t Pb = (size_t)h * S_LEN * S_LEN;
    const int tid = threadIdx.x;

    if (kt > qt) {
        f32x4 z = {0.f, 0.f, 0.f, 0.f};
        float* base = P + Pb + (size_t)(qt * 128) * S_LEN + kt * 128;
        #pragma unroll
        for (int i = 0; i < 16; i++) {
            int idx = i * 256 + tid;
            int row = idx >> 5, c = idx & 31;
            *(f32x4*)(base + (size_t)row * S_LEN + c * 4) = z;
        }
        return;
    }

    const int lane = tid & 63;
    const int w = tid >> 6;
    const int lrow = lane & 15;
    const int g = lane >> 4;
    const float c1 = 0.18033688f;
    const __bf16* ksec = qkv + 1024;

    bf16x8 qfr[2][2], kf[2][8];
    #pragma unroll
    for (int qq = 0; qq < 2; qq++)
        #pragma unroll
        for (int kk = 0; kk < 2; kk++)
            qfr[qq][kk] = *(const bf16x8*)(qkv +
                (size_t)(qt * 128 + w * 32 + qq * 16 + lrow) * 3072 + h * DK + kk * 32 + g * 8);
    #pragma unroll
    for (int mf = 0; mf < 8; mf++)
        #pragma unroll
        for (int kk = 0; kk < 2; kk++)
            kf[kk][mf] = *(const bf16x8*)(ksec +
                (size_t)(kt * 128 + mf * 16 + lrow) * 3072 + h * DK + kk * 32 + g * 8);

    f32x4 acc[2][8];
    #pragma unroll
    for (int qq = 0; qq < 2; qq++)
        #pragma unroll
        for (int mf = 0; mf < 8; mf++) acc[qq][mf] = (f32x4){0.f, 0.f, 0.f, 0.f};
    #pragma unroll
    for (int kk = 0; kk < 2; kk++)
        #pragma unroll
        for (int qq = 0; qq < 2; qq++)
            #pragma unroll
            for (int mf = 0; mf < 8; mf++)
                acc[qq][mf] = MFMA16(kf[kk][mf], qfr[qq][kk], acc[qq][mf]);

    #pragma unroll
    for (int qq = 0; qq < 2; qq++) {
        int q = qt * 128 + w * 32 + qq * 16 + lrow;
        float offv = Obuf[h * S_LEN + q];
        float* prow = P + Pb + (size_t)q * S_LEN;
        if (kt == qt) {
            #pragma unroll
            for (int mf = 0; mf < 8; mf++) {
                int kvb = kt * 128 + mf * 16 + g * 4;
                f32x4 st;
                st[0] = (kvb + 0 <= q) ? exp2f(acc[qq][mf][0] * c1 + offv) : 0.f;
                st[1] = (kvb + 1 <= q) ? exp2f(acc[qq][mf][1] * c1 + offv) : 0.f;
                st[2] = (kvb + 2 <= q) ? exp2f(acc[qq][mf][2] * c1 + offv) : 0.f;
                st[3] = (kvb + 3 <= q) ? exp2f(acc[qq][mf][3] * c1 + offv) : 0.f;
                *(f32x4*)(prow + kvb) = st;
            }
        } else {
            #pragma unroll
            for (int mf = 0; mf < 8; mf++) {
                int kvb = kt * 128 + mf * 16 + g * 4;
                f32x4 st;
                st[0] = exp2f(acc[qq][mf][0] * c1 + offv);
                st[1] = exp2f(acc[qq][mf][1] * c1 + offv);
                st[2] = exp2f(acc[qq][mf][2] * c1 + offv);
                st[3] = exp2f(acc[qq][mf][3] * c1 + offv);
                *(f32x4*)(prow + kvb) = st;
            }
        }
    }
}

// ---------------------------------------------------------------------------
extern "C" void kernel_launch(void* const* d_in, const int* in_sizes, int n_in,
                              void* d_out, int out_size, void* d_ws, size_t ws_size,
                              hipStream_t stream)
{
    const float* x     = (const float*)d_in[0];
    const float* g1    = (const float*)d_in[1];
    const float* beta1 = (const float*)d_in[2];
    const float* W_in  = (const float*)d_in[3];
    const float* b_in  = (const float*)d_in[4];
    const float* Wq    = (const float*)d_in[5];
    const float* bq    = (const float*)d_in[6];
    const float* Wk    = (const float*)d_in[7];
    const float* bk    = (const float*)d_in[8];
    const float* Wv    = (const float*)d_in[9];
    const float* bv    = (const float*)d_in[10];
    const float* Wo    = (const float*)d_in[11];
    const float* bo    = (const float*)d_in[12];
    const float* W2    = (const float*)d_in[13];
    const float* b2    = (const float*)d_in[14];
    const float* g2    = (const float*)d_in[15];
    const float* beta2 = (const float*)d_in[16];
    const float* Wf1   = (const float*)d_in[17];
    const float* bf1   = (const float*)d_in[18];
    const float* Wf2   = (const float*)d_in[19];
    const float* bf2   = (const float*)d_in[20];

    float* outp = (float*)d_out;                    // [2048][1024]
    float* Pout = outp + (size_t)S_LEN * D_MOD;     // [16][2048][2048]

    char* p = (char*)d_ws;
    auto alloc = [&](size_t b) -> void* {
        void* r = (void*)p;
        p += (b + 255) & ~(size_t)255;
        return r;
    };
    __bf16* WqkvT    = (__bf16*)alloc((size_t)3072 * 1024 * 2);
    __bf16* W2T      = (__bf16*)alloc((size_t)1024 * 1024 * 2);
    __bf16* Wf1T     = (__bf16*)alloc((size_t)D_FF * D_MOD * 2);
    __bf16* Wf2T     = (__bf16*)alloc((size_t)D_MOD * D_FF * 2);
    __bf16* WqkvCT   = (__bf16*)alloc((size_t)3072 * 1024 * 2);
    __bf16* WcombT   = (__bf16*)alloc((size_t)1024 * 1024 * 2);
    float*  bqkv     = (float*)alloc((size_t)3072 * 4);
    float*  bcomb    = (float*)alloc((size_t)1024 * 4);
    float*  biaspart = (float*)alloc((size_t)8 * 4096 * 4);
    __bf16* xn_b     = (__bf16*)alloc((size_t)S_LEN * D_MOD * 2);
    __bf16* qkv_b    = (__bf16*)alloc((size_t)S_LEN * 3072 * 2);
    __bf16* VT       = (__bf16*)alloc((size_t)N_HEADS * DK * S_LEN * 2);
    __bf16* ctx_b    = (__bf16*)alloc((size_t)S_LEN * D_MOD * 2);
    float*  part1f   = (float*)alloc((size_t)S_LEN * D_MOD * 4);
    float*  norm2f   = (float*)alloc((size_t)S_LEN * D_MOD * 4);
    __bf16* norm2b   = (__bf16*)alloc((size_t)S_LEN * D_MOD * 2);
    __bf16* ff1_b    = (__bf16*)alloc((size_t)S_LEN * D_FF * 2);
    float*  Obuf     = (float*)alloc((size_t)N_HEADS * S_LEN * 4);
    // aliases: weight staging only needed before part1f/norm2f are written
    __bf16* Win_b = (__bf16*)part1f;
    __bf16* Wo_b  = (__bf16*)norm2f;

    dim3 blk(256);

    // --- weight prep ---
    transpose_f32_bf16<<<dim3(32, 32), blk, 0, stream>>>(Wq, WqkvT, 1024, 1024);
    transpose_f32_bf16<<<dim3(32, 32), blk, 0, stream>>>(Wk, WqkvT + 1024 * 1024, 1024, 1024);
    transpose_f32_bf16<<<dim3(32, 32), blk, 0, stream>>>(Wv, WqkvT + 2 * 1024 * 1024, 1024, 1024);
    transpose_f32_bf16<<<dim3(32, 32), blk, 0, stream>>>(W2, W2T, 1024, 1024);
    transpose_f32_bf16<<<dim3(128, 32), blk, 0, stream>>>(Wf1, Wf1T, 1024, 4096);
    transpose_f32_bf16<<<dim3(32, 128), blk, 0, stream>>>(Wf2, Wf2T, 4096, 1024);
    convert_f32_bf16<<<dim3(1024), blk, 0, stream>>>(W_in, Win_b);
    convert_f32_bf16<<<dim3(1024), blk, 0, stream>>>(Wo, Wo_b);
    bias_stage1<<<dim3(16, 8), blk, 0, stream>>>(b_in, bo, Wq, Wk, Wv, W2, biaspart);
    bias_stage2<<<dim3(16), blk, 0, stream>>>(biaspart, bq, bk, bv, b2, bqkv, bcomb);

    // (Win·Wqkv)^T and (Wo·W2)^T
    gemm_kernel<64, false, false, false, true><<<dim3(16, 24), blk, 0, stream>>>(
        WqkvT, Win_b, nullptr, nullptr, nullptr, WqkvCT, 3072, 1024, 1024);
    gemm_kernel<64, false, false, false, true><<<dim3(16, 8), blk, 0, stream>>>(
        W2T, Wo_b, nullptr, nullptr, nullptr, WcombT, 1024, 1024, 1024);

    // --- forward ---
    ln_kernel<<<S_LEN, blk, 0, stream>>>(x, g1, beta1, xn_b, nullptr);

    gemm_kernel<128, false, false, false, true><<<dim3(24, 16), blk, 0, stream>>>(
        xn_b, WqkvCT, bqkv, nullptr, nullptr, qkv_b, 2048, 3072, 1024);

    vhead_transpose<<<dim3(64, 2, 16), blk, 0, stream>>>(qkv_b + 2048, VT);

    attn_flash<<<dim3(128, 16), blk, 0, stream>>>(qkv_b, VT, Obuf, ctx_b);
    attn_pwrite<<<dim3(16, 16, 16), blk, 0, stream>>>(qkv_b, Obuf, Pout);

    gemm_kernel<64, false, true, true, false><<<dim3(16, 16), blk, 0, stream>>>(
        ctx_b, WcombT, bcomb, x, part1f, nullptr, 2048, 1024, 1024);

    ln_kernel<<<S_LEN, blk, 0, stream>>>(part1f, g2, beta2, norm2b, norm2f);

    gemm_kernel<128, true, false, false, true><<<dim3(32, 16), blk, 0, stream>>>(
        norm2b, Wf1T, bf1, nullptr, nullptr, ff1_b, 2048, 4096, 1024);

    gemm_kernel<64, false, true, true, false><<<dim3(16, 16), blk, 0, stream>>>(
        ff1_b, Wf2T, bf2, norm2f, outp, nullptr, 2048, 1024, 4096);
}

// Round 9
// 382.618 us; speedup vs baseline: 1.1240x; 1.0836x over previous
//
#include <hip/hip_runtime.h>
#include <hip/hip_bf16.h>
#include <cstdint>

#define S_LEN 2048
#define D_MOD 1024
#define N_HEADS 16
#define DK 64
#define D_FF 4096

typedef __bf16 bf16x8 __attribute__((ext_vector_type(8)));
typedef float f32x4 __attribute__((ext_vector_type(4)));

#define MFMA16(a, b, c) __builtin_amdgcn_mfma_f32_16x16x32_bf16((a), (b), (c), 0, 0, 0)

__device__ inline unsigned pack_bf16x2(float a, float b)
{
    unsigned short ua = __builtin_bit_cast(unsigned short, (__bf16)a);
    unsigned short ub = __builtin_bit_cast(unsigned short, (__bf16)b);
    return (unsigned)ua | ((unsigned)ub << 16);
}

// async global->LDS, 16B per lane; LDS dest must be wave-uniform-base + lane*16
__device__ inline void gload16(const void* g, void* l)
{
    __builtin_amdgcn_global_load_lds(
        (const __attribute__((address_space(1))) unsigned int*)g,
        (__attribute__((address_space(3))) unsigned int*)l, 16, 0, 0);
}

// ---------------------------------------------------------------------------
// Fused weight transpose + f32->bf16. 1D grid of 32x32 tiles over 6 matrices.
// ---------------------------------------------------------------------------
__global__ __launch_bounds__(256)
void transpose_all(const float* __restrict__ Wq, const float* __restrict__ Wk,
                   const float* __restrict__ Wv, const float* __restrict__ W2,
                   const float* __restrict__ Wf1, const float* __restrict__ Wf2,
                   __bf16* __restrict__ WqkvT, __bf16* __restrict__ W2T,
                   __bf16* __restrict__ Wf1T, __bf16* __restrict__ Wf2T)
{
    __shared__ float tile[32][33];
    int id = blockIdx.x;
    const float* W; __bf16* WT; int K, N, n0, k0;
    if (id < 4096) {
        int m = id >> 10; id &= 1023;
        K = 1024; N = 1024;
        n0 = (id & 31) * 32; k0 = (id >> 5) * 32;
        W = m == 0 ? Wq : (m == 1 ? Wk : (m == 2 ? Wv : W2));
        WT = m == 3 ? W2T : WqkvT + (size_t)m * 1024 * 1024;
    } else if (id < 8192) {
        id -= 4096;
        K = 1024; N = 4096;
        n0 = (id & 127) * 32; k0 = (id >> 7) * 32;
        W = Wf1; WT = Wf1T;
    } else {
        id -= 8192;
        K = 4096; N = 1024;
        n0 = (id & 31) * 32; k0 = (id >> 5) * 32;
        W = Wf2; WT = Wf2T;
    }
    int tx = threadIdx.x & 31, ty = threadIdx.x >> 5;
    for (int i = 0; i < 4; i++)
        tile[ty + i * 8][tx] = W[(size_t)(k0 + ty + i * 8) * N + n0 + tx];
    __syncthreads();
    for (int i = 0; i < 4; i++)
        WT[(size_t)(n0 + ty + i * 8) * K + k0 + tx] = (__bf16)tile[tx][ty + i * 8];
}

// fused plain converts: W_in (blocks 0..1023), Wo (1024..2047)
__global__ __launch_bounds__(256)
void convert_all(const float* __restrict__ W_in, const float* __restrict__ Wo,
                 __bf16* __restrict__ Win_b, __bf16* __restrict__ Wo_b)
{
    int b = blockIdx.x;
    const float* W = b < 1024 ? W_in : Wo;
    __bf16* o = b < 1024 ? Win_b : Wo_b;
    int i = (b & 1023) * 256 + threadIdx.x;
    float4 v = ((const float4*)W)[i];
    uint2 pk;
    pk.x = pack_bf16x2(v.x, v.y);
    pk.y = pack_bf16x2(v.z, v.w);
    ((uint2*)o)[i] = pk;
}

// ---------------------------------------------------------------------------
// bias matvecs, two-stage parallel reduce
// ---------------------------------------------------------------------------
__global__ __launch_bounds__(256)
void bias_stage1(const float* __restrict__ b_in, const float* __restrict__ bo,
                 const float* __restrict__ Wq, const float* __restrict__ Wk,
                 const float* __restrict__ Wv, const float* __restrict__ W2,
                 float* __restrict__ part)
{
    int n = blockIdx.x * 256 + threadIdx.x;
    int kc = blockIdx.y;
    int sel = n >> 10, col = n & 1023;
    const float* W = sel == 0 ? Wq : (sel == 1 ? Wk : (sel == 2 ? Wv : W2));
    const float* src = sel < 3 ? b_in : bo;
    float s = 0.f;
    for (int k = kc * 128; k < kc * 128 + 128; k++)
        s += src[k] * W[(size_t)k * 1024 + col];
    part[kc * 4096 + n] = s;
}

__global__ __launch_bounds__(256)
void bias_stage2(const float* __restrict__ part,
                 const float* __restrict__ bq, const float* __restrict__ bk,
                 const float* __restrict__ bv, const float* __restrict__ b2,
                 float* __restrict__ bqkv, float* __restrict__ bcomb)
{
    int n = blockIdx.x * 256 + threadIdx.x;
    int sel = n >> 10, col = n & 1023;
    float s = sel == 0 ? bq[col] : (sel == 1 ? bk[col] : (sel == 2 ? bv[col] : b2[col]));
    for (int kc = 0; kc < 8; kc++) s += part[kc * 4096 + n];
    if (n < 3072) bqkv[n] = s; else bcomb[col] = s;
}

// ---------------------------------------------------------------------------
// Per-head V transpose: qkv v-section [s][3072] -> VT[h][d][s] bf16
// ---------------------------------------------------------------------------
__global__ __launch_bounds__(256)
void vhead_transpose(const __bf16* __restrict__ v, __bf16* __restrict__ vt)
{
    __shared__ __bf16 tile[32][33];
    int tx = threadIdx.x & 31, ty = threadIdx.x >> 5;
    int s0 = blockIdx.x * 32;
    int d0 = blockIdx.y * 32;
    int h = blockIdx.z;
    for (int i = 0; i < 4; i++)
        tile[ty + i * 8][tx] = v[(size_t)(s0 + ty + i * 8) * 3072 + h * DK + d0 + tx];
    __syncthreads();
    for (int i = 0; i < 4; i++)
        vt[(size_t)(h * DK + d0 + ty + i * 8) * S_LEN + s0 + tx] = tile[tx][ty + i * 8];
}

// ---------------------------------------------------------------------------
// LayerNorm
// ---------------------------------------------------------------------------
__global__ __launch_bounds__(256)
void ln_kernel(const float* __restrict__ x, const float* __restrict__ gamma,
               const float* __restrict__ beta, __bf16* __restrict__ outb,
               float* __restrict__ outf)
{
    int row = blockIdx.x;
    int tid = threadIdx.x;
    const float4 v = ((const float4*)(x + (size_t)row * D_MOD))[tid];
    float s = v.x + v.y + v.z + v.w;
    float sq = v.x * v.x + v.y * v.y + v.z * v.z + v.w * v.w;
    for (int off = 32; off; off >>= 1) {
        s += __shfl_down(s, off);
        sq += __shfl_down(sq, off);
    }
    __shared__ float red[8];
    int wid = tid >> 6;
    if ((tid & 63) == 0) { red[wid] = s; red[wid + 4] = sq; }
    __syncthreads();
    s = red[0] + red[1] + red[2] + red[3];
    sq = red[4] + red[5] + red[6] + red[7];
    float mean = s * (1.f / D_MOD);
    float var = sq * (1.f / D_MOD) - mean * mean;
    var = fmaxf(var, 0.f);
    float inv = 1.f / (sqrtf(var) + 1e-6f);
    float4 gv = ((const float4*)gamma)[tid];
    float4 bv = ((const float4*)beta)[tid];
    float y0 = gv.x * ((v.x - mean) * inv) + bv.x;
    float y1 = gv.y * ((v.y - mean) * inv) + bv.y;
    float y2 = gv.z * ((v.z - mean) * inv) + bv.z;
    float y3 = gv.w * ((v.w - mean) * inv) + bv.w;
    uint2 pk;
    pk.x = pack_bf16x2(y0, y1);
    pk.y = pack_bf16x2(y2, y3);
    ((uint2*)(outb + (size_t)row * D_MOD))[tid] = pk;
    if (outf) {
        float4 o = {y0, y1, y2, y3};
        ((float4*)(outf + (size_t)row * D_MOD))[tid] = o;
    }
}

// ---------------------------------------------------------------------------
// GEMM: C[M][N] = A[M][Kst](bf16, loop Klp) * BT[N][Kst] + bias
// ---------------------------------------------------------------------------
template<int BN, bool RELU, bool RES, bool RES2, bool WF32, bool WBF16>
__global__ __launch_bounds__(256, 2)
void gemm_kernel(const __bf16* __restrict__ A, const __bf16* __restrict__ BT,
                 const float* __restrict__ bias, const float* __restrict__ res,
                 const float* __restrict__ res2,
                 float* __restrict__ Cf, __bf16* __restrict__ Cb,
                 int M, int N, int Kst, int Klp)
{
    constexpr int NFRAG = BN / 32;
    __shared__ uint4 As[128 * 8];
    __shared__ uint4 Bs[BN * 8];
    const int tid = threadIdx.x;
    const int lane = tid & 63;
    const int w = tid >> 6;
    const int lrow = lane & 15;
    const int g = lane >> 4;
    const int bm = blockIdx.y * 128;
    const int bn = blockIdx.x * BN;
    const int wrow = (w >> 1) * 64;
    const int wcol = (w & 1) * (BN / 2);

    f32x4 acc[4][NFRAG];
    for (int m = 0; m < 4; m++)
        for (int n = 0; n < NFRAG; n++)
            acc[m][n] = (f32x4){0.f, 0.f, 0.f, 0.f};

    const int srow = tid >> 3;
    const int sc = tid & 7;
    const __bf16* Ag = A + (size_t)(bm + srow) * Kst + sc * 8;
    const __bf16* Bg = BT + (size_t)(bn + srow) * Kst + sc * 8;

    for (int kt = 0; kt < Klp; kt += 64) {
        __syncthreads();
        #pragma unroll
        for (int p = 0; p < 4; p++)
            gload16(Ag + (size_t)(p * 32) * Kst + kt, &As[(srow + p * 32) * 8 + sc]);
        #pragma unroll
        for (int p = 0; p < NFRAG; p++)
            gload16(Bg + (size_t)(p * 32) * Kst + kt, &Bs[(srow + p * 32) * 8 + sc]);
        asm volatile("s_waitcnt vmcnt(0)" ::: "memory");
        __syncthreads();
        #pragma unroll
        for (int kk = 0; kk < 2; kk++) {
            bf16x8 af[4], bfr[NFRAG];
            int c = kk * 4 + g;
            #pragma unroll
            for (int m = 0; m < 4; m++)
                af[m] = __builtin_bit_cast(bf16x8, As[(wrow + m * 16 + lrow) * 8 + c]);
            #pragma unroll
            for (int n = 0; n < NFRAG; n++)
                bfr[n] = __builtin_bit_cast(bf16x8, Bs[(wcol + n * 16 + lrow) * 8 + c]);
            #pragma unroll
            for (int m = 0; m < 4; m++)
                #pragma unroll
                for (int n = 0; n < NFRAG; n++)
                    acc[m][n] = MFMA16(af[m], bfr[n], acc[m][n]);
        }
    }

    for (int n = 0; n < NFRAG; n++) {
        int col = bn + wcol + n * 16 + lrow;
        float bval = bias ? bias[col] : 0.f;
        for (int m = 0; m < 4; m++) {
            int row0 = bm + wrow + m * 16 + g * 4;
            for (int r = 0; r < 4; r++) {
                int row = row0 + r;
                float v = acc[m][n][r] + bval;
                if (RELU) v = fmaxf(v, 0.f);
                if (RES) v += res[(size_t)row * N + col];
                if (RES2) v += res2[(size_t)row * N + col];
                if (WF32) Cf[(size_t)row * N + col] = v;
                if (WBF16) Cb[(size_t)row * N + col] = (__bf16)v;
            }
        }
    }
}

// ---------------------------------------------------------------------------
// attn_flash: single-pass online-softmax flash attention (no P write).
// Block = (16-row band, head), 4 waves split kv tiles. Outputs ctx (bf16)
// and Obuf[h][q] = -M - log2(L) for the P-writer.
// ---------------------------------------------------------------------------
__global__ __launch_bounds__(256)
void attn_flash(const __bf16* __restrict__ qkv, const __bf16* __restrict__ vt,
                float* __restrict__ Obuf, __bf16* __restrict__ ctx)
{
    __shared__ char Plds[4][4096];
    __shared__ float cmw[4][16], clw[4][16], Linv[16];
    const int tid = threadIdx.x;
    const int lane = tid & 63;
    const int w = tid >> 6;
    const int lrow = lane & 15;
    const int g = lane >> 4;
    const int band = 127 - (int)blockIdx.x;   // heavy first
    const int h = blockIdx.y;
    const int qg = band * 16 + lrow;
    const int ntiles = band / 8 + 1;
    const float c1 = 0.18033688f;             // 0.125 * log2(e)

    const __bf16* ksec = qkv + 1024;
    char* plB = Plds[w];

    bf16x8 qf[2];
    qf[0] = *(const bf16x8*)(qkv + (size_t)qg * 3072 + h * DK + g * 8);
    qf[1] = *(const bf16x8*)(qkv + (size_t)qg * 3072 + h * DK + 32 + g * 8);

    float m2 = -1e30f, l = 0.f;
    f32x4 acc2[4];
    #pragma unroll
    for (int i = 0; i < 4; i++) acc2[i] = (f32x4){0.f, 0.f, 0.f, 0.f};

    for (int kt = w; kt < ntiles; kt += 4) {
        f32x4 acc[8];
        #pragma unroll
        for (int mf = 0; mf < 8; mf++) acc[mf] = (f32x4){0.f, 0.f, 0.f, 0.f};
        const __bf16* kbase = ksec + (size_t)(kt * 128 + lrow) * 3072 + h * DK + g * 8;
        #pragma unroll
        for (int kk = 0; kk < 2; kk++)
            #pragma unroll
            for (int mf = 0; mf < 8; mf++) {
                bf16x8 kf = *(const bf16x8*)(kbase + (size_t)(mf * 16) * 3072 + kk * 32);
                acc[mf] = MFMA16(kf, qf[kk], acc[mf]);
            }
        float s[8][4], mx[8];
        #pragma unroll
        for (int mf = 0; mf < 8; mf++) {
            int kvb = kt * 128 + mf * 16 + g * 4;
            #pragma unroll
            for (int r = 0; r < 4; r++)
                s[mf][r] = (kvb + r <= qg) ? acc[mf][r] * c1 : -1e30f;
            mx[mf] = fmaxf(fmaxf(s[mf][0], s[mf][1]), fmaxf(s[mf][2], s[mf][3]));
        }
        float tm = fmaxf(fmaxf(fmaxf(mx[0], mx[1]), fmaxf(mx[2], mx[3])),
                         fmaxf(fmaxf(mx[4], mx[5]), fmaxf(mx[6], mx[7])));
        tm = fmaxf(tm, __shfl_xor(tm, 16));
        tm = fmaxf(tm, __shfl_xor(tm, 32));
        float nm = fmaxf(m2, tm);
        float scale = exp2f(m2 - nm);
        m2 = nm;
        float sum = 0.f;
        #pragma unroll
        for (int mf = 0; mf < 8; mf++) {
            float p0 = exp2f(s[mf][0] - nm);
            float p1 = exp2f(s[mf][1] - nm);
            float p2 = exp2f(s[mf][2] - nm);
            float p3 = exp2f(s[mf][3] - nm);
            sum += (p0 + p1) + (p2 + p3);
            uint2 pk;
            pk.x = pack_bf16x2(p0, p1);
            pk.y = pack_bf16x2(p2, p3);
            *(uint2*)(plB + ((lrow * 256 + mf * 32 + g * 8) ^ ((lrow & 7) << 4))) = pk;
        }
        l = l * scale + sum;
        #pragma unroll
        for (int md = 0; md < 4; md++) acc2[md] *= scale;
        #pragma unroll
        for (int ks = 0; ks < 4; ks++) {
            bf16x8 pf = *(bf16x8*)(plB + ((lrow * 256 + ks * 64 + g * 16) ^ ((lrow & 7) << 4)));
            const __bf16* vp = vt + (size_t)(h * DK + lrow) * S_LEN + kt * 128 + ks * 32 + g * 8;
            #pragma unroll
            for (int md = 0; md < 4; md++) {
                bf16x8 vf = *(const bf16x8*)(vp + (size_t)(md * 16) * S_LEN);
                acc2[md] = MFMA16(vf, pf, acc2[md]);
            }
        }
    }

    l += __shfl_xor(l, 16);
    l += __shfl_xor(l, 32);
    if (lane < 16) { cmw[w][lrow] = m2; clw[w][lrow] = l; }
    __syncthreads();
    float M = fmaxf(fmaxf(cmw[0][lrow], cmw[1][lrow]), fmaxf(cmw[2][lrow], cmw[3][lrow]));
    float L = clw[0][lrow] * exp2f(cmw[0][lrow] - M)
            + clw[1][lrow] * exp2f(cmw[1][lrow] - M)
            + clw[2][lrow] * exp2f(cmw[2][lrow] - M)
            + clw[3][lrow] * exp2f(cmw[3][lrow] - M);
    {
        float sw = exp2f(m2 - M);
        float* rv = (float*)plB;
        #pragma unroll
        for (int md = 0; md < 4; md++) {
            int off = (md * 16 + g * 4) ^ ((lrow & 7) << 3);
            f32x4 t = acc2[md] * sw;
            *(f32x4*)(rv + lrow * 64 + off) = t;
        }
    }
    if (w == 0 && lane < 16) {
        Obuf[h * S_LEN + qg] = -M - log2f(L);
        Linv[lrow] = 1.f / L;
    }
    __syncthreads();
    {
        int q = tid >> 4, d0 = (tid & 15) * 4;
        int off = q * 64 + (d0 ^ ((q & 7) << 3));
        f32x4 v = *(const f32x4*)((const float*)Plds[0] + off);
        v += *(const f32x4*)((const float*)Plds[1] + off);
        v += *(const f32x4*)((const float*)Plds[2] + off);
        v += *(const f32x4*)((const float*)Plds[3] + off);
        float li = Linv[q];
        uint2 pk;
        pk.x = pack_bf16x2(v[0] * li, v[1] * li);
        pk.y = pack_bf16x2(v[2] * li, v[3] * li);
        *(uint2*)(ctx + (size_t)(band * 16 + q) * D_MOD + h * DK + d0) = pk;
    }
}

// ---------------------------------------------------------------------------
// ff1_pwrite: heterogeneous kernel. Blocks [0,512): ff1 GEMM
// (relu(norm2 @ Wf1 + bf1) -> bf16). Blocks [512, 512+4096): P materialize
// (zero-fill or QK^T+exp2, nontemporal stores). The two groups are
// independent; GEMM blocks dispatch first, pwrite backfills -> BW/compute
// overlap on the device.
// ---------------------------------------------------------------------------
__global__ __launch_bounds__(256)
void ff1_pwrite(const __bf16* __restrict__ A, const __bf16* __restrict__ BT,
                const float* __restrict__ bias, __bf16* __restrict__ Cb,
                const __bf16* __restrict__ qkv, const float* __restrict__ Obuf,
                float* __restrict__ P)
{
    __shared__ uint4 As[128 * 8];
    __shared__ uint4 Bs[128 * 8];
    const int tid = threadIdx.x;
    const int lane = tid & 63;
    const int w = tid >> 6;
    const int lrow = lane & 15;
    const int g = lane >> 4;

    if (blockIdx.x < 512) {
        // ---------------- ff1 GEMM: M=2048 N=4096 K=1024, BN=128 ----------------
        const int bid = blockIdx.x;
        const int bm = (bid >> 5) * 128;
        const int bn = (bid & 31) * 128;
        const int wrow = (w >> 1) * 64;
        const int wcol = (w & 1) * 64;
        f32x4 acc[4][4];
        for (int m = 0; m < 4; m++)
            for (int n = 0; n < 4; n++)
                acc[m][n] = (f32x4){0.f, 0.f, 0.f, 0.f};
        const int srow = tid >> 3;
        const int sc = tid & 7;
        const __bf16* Ag = A + (size_t)(bm + srow) * 1024 + sc * 8;
        const __bf16* Bg = BT + (size_t)(bn + srow) * 1024 + sc * 8;
        for (int kt = 0; kt < 1024; kt += 64) {
            __syncthreads();
            #pragma unroll
            for (int p = 0; p < 4; p++)
                gload16(Ag + (size_t)(p * 32) * 1024 + kt, &As[(srow + p * 32) * 8 + sc]);
            #pragma unroll
            for (int p = 0; p < 4; p++)
                gload16(Bg + (size_t)(p * 32) * 1024 + kt, &Bs[(srow + p * 32) * 8 + sc]);
            asm volatile("s_waitcnt vmcnt(0)" ::: "memory");
            __syncthreads();
            #pragma unroll
            for (int kk = 0; kk < 2; kk++) {
                bf16x8 af[4], bfr[4];
                int c = kk * 4 + g;
                #pragma unroll
                for (int m = 0; m < 4; m++)
                    af[m] = __builtin_bit_cast(bf16x8, As[(wrow + m * 16 + lrow) * 8 + c]);
                #pragma unroll
                for (int n = 0; n < 4; n++)
                    bfr[n] = __builtin_bit_cast(bf16x8, Bs[(wcol + n * 16 + lrow) * 8 + c]);
                #pragma unroll
                for (int m = 0; m < 4; m++)
                    #pragma unroll
                    for (int n = 0; n < 4; n++)
                        acc[m][n] = MFMA16(af[m], bfr[n], acc[m][n]);
            }
        }
        for (int n = 0; n < 4; n++) {
            int col = bn + wcol + n * 16 + lrow;
            float bval = bias[col];
            for (int m = 0; m < 4; m++) {
                int row0 = bm + wrow + m * 16 + g * 4;
                for (int r = 0; r < 4; r++) {
                    float v = fmaxf(acc[m][n][r] + bval, 0.f);
                    Cb[(size_t)(row0 + r) * D_FF + col] = (__bf16)v;
                }
            }
        }
        return;
    }

    // ---------------- P materialization ----------------
    const int id2 = blockIdx.x - 512;
    const int kt = id2 & 15, qt = (id2 >> 4) & 15, h = id2 >> 8;
    const size_t Pb = (size_t)h * S_LEN * S_LEN;

    if (kt > qt) {
        f32x4 z = {0.f, 0.f, 0.f, 0.f};
        float* base = P + Pb + (size_t)(qt * 128) * S_LEN + kt * 128;
        #pragma unroll
        for (int i = 0; i < 16; i++) {
            int idx = i * 256 + tid;
            int row = idx >> 5, c = idx & 31;
            __builtin_nontemporal_store(z, (f32x4*)(base + (size_t)row * S_LEN + c * 4));
        }
        return;
    }

    const float c1 = 0.18033688f;
    const __bf16* ksec = qkv + 1024;

    bf16x8 qfr[2][2];
    #pragma unroll
    for (int qq = 0; qq < 2; qq++)
        #pragma unroll
        for (int kk = 0; kk < 2; kk++)
            qfr[qq][kk] = *(const bf16x8*)(qkv +
                (size_t)(qt * 128 + w * 32 + qq * 16 + lrow) * 3072 + h * DK + kk * 32 + g * 8);

    f32x4 acc[2][8];
    #pragma unroll
    for (int qq = 0; qq < 2; qq++)
        #pragma unroll
        for (int mf = 0; mf < 8; mf++) acc[qq][mf] = (f32x4){0.f, 0.f, 0.f, 0.f};
    #pragma unroll
    for (int kk = 0; kk < 2; kk++) {
        #pragma unroll
        for (int mf = 0; mf < 8; mf++) {
            bf16x8 kf = *(const bf16x8*)(ksec +
                (size_t)(kt * 128 + mf * 16 + lrow) * 3072 + h * DK + kk * 32 + g * 8);
            acc[0][mf] = MFMA16(kf, qfr[0][kk], acc[0][mf]);
            acc[1][mf] = MFMA16(kf, qfr[1][kk], acc[1][mf]);
        }
    }

    #pragma unroll
    for (int qq = 0; qq < 2; qq++) {
        int q = qt * 128 + w * 32 + qq * 16 + lrow;
        float offv = Obuf[h * S_LEN + q];
        float* prow = P + Pb + (size_t)q * S_LEN;
        if (kt == qt) {
            #pragma unroll
            for (int mf = 0; mf < 8; mf++) {
                int kvb = kt * 128 + mf * 16 + g * 4;
                f32x4 st;
                st[0] = (kvb + 0 <= q) ? exp2f(acc[qq][mf][0] * c1 + offv) : 0.f;
                st[1] = (kvb + 1 <= q) ? exp2f(acc[qq][mf][1] * c1 + offv) : 0.f;
                st[2] = (kvb + 2 <= q) ? exp2f(acc[qq][mf][2] * c1 + offv) : 0.f;
                st[3] = (kvb + 3 <= q) ? exp2f(acc[qq][mf][3] * c1 + offv) : 0.f;
                __builtin_nontemporal_store(st, (f32x4*)(prow + kvb));
            }
        } else {
            #pragma unroll
            for (int mf = 0; mf < 8; mf++) {
                int kvb = kt * 128 + mf * 16 + g * 4;
                f32x4 st;
                st[0] = exp2f(acc[qq][mf][0] * c1 + offv);
                st[1] = exp2f(acc[qq][mf][1] * c1 + offv);
                st[2] = exp2f(acc[qq][mf][2] * c1 + offv);
                st[3] = exp2f(acc[qq][mf][3] * c1 + offv);
                __builtin_nontemporal_store(st, (f32x4*)(prow + kvb));
            }
        }
    }
}

// ---------------------------------------------------------------------------
extern "C" void kernel_launch(void* const* d_in, const int* in_sizes, int n_in,
                              void* d_out, int out_size, void* d_ws, size_t ws_size,
                              hipStream_t stream)
{
    const float* x     = (const float*)d_in[0];
    const float* g1    = (const float*)d_in[1];
    const float* beta1 = (const float*)d_in[2];
    const float* W_in  = (const float*)d_in[3];
    const float* b_in  = (const float*)d_in[4];
    const float* Wq    = (const float*)d_in[5];
    const float* bq    = (const float*)d_in[6];
    const float* Wk    = (const float*)d_in[7];
    const float* bk    = (const float*)d_in[8];
    const float* Wv    = (const float*)d_in[9];
    const float* bv    = (const float*)d_in[10];
    const float* Wo    = (const float*)d_in[11];
    const float* bo    = (const float*)d_in[12];
    const float* W2    = (const float*)d_in[13];
    const float* b2    = (const float*)d_in[14];
    const float* g2    = (const float*)d_in[15];
    const float* beta2 = (const float*)d_in[16];
    const float* Wf1   = (const float*)d_in[17];
    const float* bf1   = (const float*)d_in[18];
    const float* Wf2   = (const float*)d_in[19];
    const float* bf2   = (const float*)d_in[20];

    float* outp = (float*)d_out;                    // [2048][1024]
    float* Pout = outp + (size_t)S_LEN * D_MOD;     // [16][2048][2048]

    char* p = (char*)d_ws;
    auto alloc = [&](size_t b) -> void* {
        void* r = (void*)p;
        p += (b + 255) & ~(size_t)255;
        return r;
    };
    __bf16* WqkvT    = (__bf16*)alloc((size_t)3072 * 1024 * 2);
    __bf16* W2T      = (__bf16*)alloc((size_t)1024 * 1024 * 2);
    __bf16* Wf1T     = (__bf16*)alloc((size_t)D_FF * D_MOD * 2);
    __bf16* Wf2T     = (__bf16*)alloc((size_t)D_MOD * D_FF * 2);
    __bf16* WqkvCT   = (__bf16*)alloc((size_t)3072 * 1024 * 2);
    __bf16* WcombT   = (__bf16*)alloc((size_t)1024 * 1024 * 2);
    float*  bqkv     = (float*)alloc((size_t)3072 * 4);
    float*  bcomb    = (float*)alloc((size_t)1024 * 4);
    float*  biaspart = (float*)alloc((size_t)8 * 4096 * 4);
    __bf16* xn_b     = (__bf16*)alloc((size_t)S_LEN * D_MOD * 2);
    __bf16* qkv_b    = (__bf16*)alloc((size_t)S_LEN * 3072 * 2);
    __bf16* VT       = (__bf16*)alloc((size_t)N_HEADS * DK * S_LEN * 2);
    __bf16* ctx_b    = (__bf16*)alloc((size_t)S_LEN * D_MOD * 2);
    float*  part1f   = (float*)alloc((size_t)S_LEN * D_MOD * 4);
    float*  norm2f   = (float*)alloc((size_t)S_LEN * D_MOD * 4);
    __bf16* norm2b   = (__bf16*)alloc((size_t)S_LEN * D_MOD * 2);
    __bf16* ff1_b    = (__bf16*)alloc((size_t)S_LEN * D_FF * 2);
    float*  Obuf     = (float*)alloc((size_t)N_HEADS * S_LEN * 4);
    // aliases (lifetimes disjoint, stream-ordered):
    __bf16* Win_b  = (__bf16*)part1f;   // weight staging before part1 GEMM
    __bf16* Wo_b   = (__bf16*)norm2f;   // weight staging before ln2
    float*  ffpart = part1f;            // split-K partial after ln2 consumed part1f

    dim3 blk(256);

    // --- weight prep (2 launches + 2 bias) ---
    transpose_all<<<dim3(12288), blk, 0, stream>>>(Wq, Wk, Wv, W2, Wf1, Wf2,
                                                   WqkvT, W2T, Wf1T, Wf2T);
    convert_all<<<dim3(2048), blk, 0, stream>>>(W_in, Wo, Win_b, Wo_b);
    bias_stage1<<<dim3(16, 8), blk, 0, stream>>>(b_in, bo, Wq, Wk, Wv, W2, biaspart);
    bias_stage2<<<dim3(16), blk, 0, stream>>>(biaspart, bq, bk, bv, b2, bqkv, bcomb);

    // (Win·Wqkv)^T and (Wo·W2)^T
    gemm_kernel<64, false, false, false, false, true><<<dim3(16, 24), blk, 0, stream>>>(
        WqkvT, Win_b, nullptr, nullptr, nullptr, nullptr, WqkvCT, 3072, 1024, 1024, 1024);
    gemm_kernel<64, false, false, false, false, true><<<dim3(16, 8), blk, 0, stream>>>(
        W2T, Wo_b, nullptr, nullptr, nullptr, nullptr, WcombT, 1024, 1024, 1024, 1024);

    // --- forward ---
    ln_kernel<<<S_LEN, blk, 0, stream>>>(x, g1, beta1, xn_b, nullptr);

    gemm_kernel<128, false, false, false, false, true><<<dim3(24, 16), blk, 0, stream>>>(
        xn_b, WqkvCT, bqkv, nullptr, nullptr, nullptr, qkv_b, 2048, 3072, 1024, 1024);

    vhead_transpose<<<dim3(64, 2, 16), blk, 0, stream>>>(qkv_b + 2048, VT);

    attn_flash<<<dim3(128, 16), blk, 0, stream>>>(qkv_b, VT, Obuf, ctx_b);

    gemm_kernel<64, false, true, false, true, false><<<dim3(16, 16), blk, 0, stream>>>(
        ctx_b, WcombT, bcomb, x, nullptr, part1f, nullptr, 2048, 1024, 1024, 1024);

    ln_kernel<<<S_LEN, blk, 0, stream>>>(part1f, g2, beta2, norm2b, norm2f);

    // ff1 GEMM + P materialization, one heterogeneous launch
    ff1_pwrite<<<dim3(512 + 4096), blk, 0, stream>>>(
        norm2b, Wf1T, bf1, ff1_b, qkv_b, Obuf, Pout);

    // ff2 split-K: K half 1 -> ffpart (f32), half 2 adds norm2 + ffpart + bias
    gemm_kernel<64, false, false, false, true, false><<<dim3(16, 16), blk, 0, stream>>>(
        ff1_b, Wf2T, nullptr, nullptr, nullptr, ffpart, nullptr, 2048, 1024, 4096, 2048);
    gemm_kernel<64, false, true, true, true, false><<<dim3(16, 16), blk, 0, stream>>>(
        ff1_b + 2048, Wf2T + 2048, bf2, norm2f, ffpart, outp, nullptr, 2048, 1024, 4096, 2048);
}

// Round 10
// 312.062 us; speedup vs baseline: 1.3781x; 1.2261x over previous
//
#include <hip/hip_runtime.h>
#include <hip/hip_bf16.h>
#include <cstdint>

#define S_LEN 2048
#define D_MOD 1024
#define N_HEADS 16
#define DK 64
#define D_FF 4096

typedef __bf16 bf16x8 __attribute__((ext_vector_type(8)));
typedef float f32x4 __attribute__((ext_vector_type(4)));

#define MFMA16(a, b, c) __builtin_amdgcn_mfma_f32_16x16x32_bf16((a), (b), (c), 0, 0, 0)

__device__ inline unsigned pack_bf16x2(float a, float b)
{
    unsigned short ua = __builtin_bit_cast(unsigned short, (__bf16)a);
    unsigned short ub = __builtin_bit_cast(unsigned short, (__bf16)b);
    return (unsigned)ua | ((unsigned)ub << 16);
}

// async global->LDS, 16B per lane; LDS dest must equal waveBase + lane*16
__device__ inline void gload16(const void* g, void* l)
{
    __builtin_amdgcn_global_load_lds(
        (const __attribute__((address_space(1))) unsigned int*)g,
        (__attribute__((address_space(3))) unsigned int*)l, 16, 0, 0);
}

// ---------------------------------------------------------------------------
// Fused weight transpose + f32->bf16. 1D grid of 32x32 tiles over 6 matrices.
// ---------------------------------------------------------------------------
__global__ __launch_bounds__(256)
void transpose_all(const float* __restrict__ Wq, const float* __restrict__ Wk,
                   const float* __restrict__ Wv, const float* __restrict__ W2,
                   const float* __restrict__ Wf1, const float* __restrict__ Wf2,
                   __bf16* __restrict__ WqkvT, __bf16* __restrict__ W2T,
                   __bf16* __restrict__ Wf1T, __bf16* __restrict__ Wf2T)
{
    __shared__ float tile[32][33];
    int id = blockIdx.x;
    const float* W; __bf16* WT; int K, N, n0, k0;
    if (id < 4096) {
        int m = id >> 10; id &= 1023;
        K = 1024; N = 1024;
        n0 = (id & 31) * 32; k0 = (id >> 5) * 32;
        W = m == 0 ? Wq : (m == 1 ? Wk : (m == 2 ? Wv : W2));
        WT = m == 3 ? W2T : WqkvT + (size_t)m * 1024 * 1024;
    } else if (id < 8192) {
        id -= 4096;
        K = 1024; N = 4096;
        n0 = (id & 127) * 32; k0 = (id >> 7) * 32;
        W = Wf1; WT = Wf1T;
    } else {
        id -= 8192;
        K = 4096; N = 1024;
        n0 = (id & 31) * 32; k0 = (id >> 5) * 32;
        W = Wf2; WT = Wf2T;
    }
    int tx = threadIdx.x & 31, ty = threadIdx.x >> 5;
    for (int i = 0; i < 4; i++)
        tile[ty + i * 8][tx] = W[(size_t)(k0 + ty + i * 8) * N + n0 + tx];
    __syncthreads();
    for (int i = 0; i < 4; i++)
        WT[(size_t)(n0 + ty + i * 8) * K + k0 + tx] = (__bf16)tile[tx][ty + i * 8];
}

// fused plain converts: W_in (blocks 0..1023), Wo (1024..2047)
__global__ __launch_bounds__(256)
void convert_all(const float* __restrict__ W_in, const float* __restrict__ Wo,
                 __bf16* __restrict__ Win_b, __bf16* __restrict__ Wo_b)
{
    int b = blockIdx.x;
    const float* W = b < 1024 ? W_in : Wo;
    __bf16* o = b < 1024 ? Win_b : Wo_b;
    int i = (b & 1023) * 256 + threadIdx.x;
    float4 v = ((const float4*)W)[i];
    uint2 pk;
    pk.x = pack_bf16x2(v.x, v.y);
    pk.y = pack_bf16x2(v.z, v.w);
    ((uint2*)o)[i] = pk;
}

// ---------------------------------------------------------------------------
// bias matvecs, two-stage parallel reduce
// ---------------------------------------------------------------------------
__global__ __launch_bounds__(256)
void bias_stage1(const float* __restrict__ b_in, const float* __restrict__ bo,
                 const float* __restrict__ Wq, const float* __restrict__ Wk,
                 const float* __restrict__ Wv, const float* __restrict__ W2,
                 float* __restrict__ part)
{
    int n = blockIdx.x * 256 + threadIdx.x;
    int kc = blockIdx.y;
    int sel = n >> 10, col = n & 1023;
    const float* W = sel == 0 ? Wq : (sel == 1 ? Wk : (sel == 2 ? Wv : W2));
    const float* src = sel < 3 ? b_in : bo;
    float s = 0.f;
    for (int k = kc * 128; k < kc * 128 + 128; k++)
        s += src[k] * W[(size_t)k * 1024 + col];
    part[kc * 4096 + n] = s;
}

__global__ __launch_bounds__(256)
void bias_stage2(const float* __restrict__ part,
                 const float* __restrict__ bq, const float* __restrict__ bk,
                 const float* __restrict__ bv, const float* __restrict__ b2,
                 float* __restrict__ bqkv, float* __restrict__ bcomb)
{
    int n = blockIdx.x * 256 + threadIdx.x;
    int sel = n >> 10, col = n & 1023;
    float s = sel == 0 ? bq[col] : (sel == 1 ? bk[col] : (sel == 2 ? bv[col] : b2[col]));
    for (int kc = 0; kc < 8; kc++) s += part[kc * 4096 + n];
    if (n < 3072) bqkv[n] = s; else bcomb[col] = s;
}

// ---------------------------------------------------------------------------
// Per-head V transpose: qkv v-section [s][3072] -> VT[h][d][s] bf16
// ---------------------------------------------------------------------------
__global__ __launch_bounds__(256)
void vhead_transpose(const __bf16* __restrict__ v, __bf16* __restrict__ vt)
{
    __shared__ __bf16 tile[32][33];
    int tx = threadIdx.x & 31, ty = threadIdx.x >> 5;
    int s0 = blockIdx.x * 32;
    int d0 = blockIdx.y * 32;
    int h = blockIdx.z;
    for (int i = 0; i < 4; i++)
        tile[ty + i * 8][tx] = v[(size_t)(s0 + ty + i * 8) * 3072 + h * DK + d0 + tx];
    __syncthreads();
    for (int i = 0; i < 4; i++)
        vt[(size_t)(h * DK + d0 + ty + i * 8) * S_LEN + s0 + tx] = tile[tx][ty + i * 8];
}

// ---------------------------------------------------------------------------
// LayerNorm
// ---------------------------------------------------------------------------
__global__ __launch_bounds__(256)
void ln_kernel(const float* __restrict__ x, const float* __restrict__ gamma,
               const float* __restrict__ beta, __bf16* __restrict__ outb,
               float* __restrict__ outf)
{
    int row = blockIdx.x;
    int tid = threadIdx.x;
    const float4 v = ((const float4*)(x + (size_t)row * D_MOD))[tid];
    float s = v.x + v.y + v.z + v.w;
    float sq = v.x * v.x + v.y * v.y + v.z * v.z + v.w * v.w;
    for (int off = 32; off; off >>= 1) {
        s += __shfl_down(s, off);
        sq += __shfl_down(sq, off);
    }
    __shared__ float red[8];
    int wid = tid >> 6;
    if ((tid & 63) == 0) { red[wid] = s; red[wid + 4] = sq; }
    __syncthreads();
    s = red[0] + red[1] + red[2] + red[3];
    sq = red[4] + red[5] + red[6] + red[7];
    float mean = s * (1.f / D_MOD);
    float var = sq * (1.f / D_MOD) - mean * mean;
    var = fmaxf(var, 0.f);
    float inv = 1.f / (sqrtf(var) + 1e-6f);
    float4 gv = ((const float4*)gamma)[tid];
    float4 bv = ((const float4*)beta)[tid];
    float y0 = gv.x * ((v.x - mean) * inv) + bv.x;
    float y1 = gv.y * ((v.y - mean) * inv) + bv.y;
    float y2 = gv.z * ((v.z - mean) * inv) + bv.z;
    float y3 = gv.w * ((v.w - mean) * inv) + bv.w;
    uint2 pk;
    pk.x = pack_bf16x2(y0, y1);
    pk.y = pack_bf16x2(y2, y3);
    ((uint2*)(outb + (size_t)row * D_MOD))[tid] = pk;
    if (outf) {
        float4 o = {y0, y1, y2, y3};
        ((float4*)(outf + (size_t)row * D_MOD))[tid] = o;
    }
}

// ---------------------------------------------------------------------------
// GEMM: C[M][N] = A[M][Kst](bf16, loop Klp) * BT[N][Kst] + bias
// ---------------------------------------------------------------------------
template<int BN, bool RELU, bool RES, bool RES2, bool WF32, bool WBF16>
__global__ __launch_bounds__(256, 2)
void gemm_kernel(const __bf16* __restrict__ A, const __bf16* __restrict__ BT,
                 const float* __restrict__ bias, const float* __restrict__ res,
                 const float* __restrict__ res2,
                 float* __restrict__ Cf, __bf16* __restrict__ Cb,
                 int M, int N, int Kst, int Klp)
{
    constexpr int NFRAG = BN / 32;
    __shared__ uint4 As[128 * 8];
    __shared__ uint4 Bs[BN * 8];
    const int tid = threadIdx.x;
    const int lane = tid & 63;
    const int w = tid >> 6;
    const int lrow = lane & 15;
    const int g = lane >> 4;
    const int bm = blockIdx.y * 128;
    const int bn = blockIdx.x * BN;
    const int wrow = (w >> 1) * 64;
    const int wcol = (w & 1) * (BN / 2);

    f32x4 acc[4][NFRAG];
    for (int m = 0; m < 4; m++)
        for (int n = 0; n < NFRAG; n++)
            acc[m][n] = (f32x4){0.f, 0.f, 0.f, 0.f};

    const int srow = tid >> 3;
    const int sc = tid & 7;
    const __bf16* Ag = A + (size_t)(bm + srow) * Kst + sc * 8;
    const __bf16* Bg = BT + (size_t)(bn + srow) * Kst + sc * 8;

    for (int kt = 0; kt < Klp; kt += 64) {
        __syncthreads();
        #pragma unroll
        for (int p = 0; p < 4; p++)
            gload16(Ag + (size_t)(p * 32) * Kst + kt, &As[(srow + p * 32) * 8 + sc]);
        #pragma unroll
        for (int p = 0; p < NFRAG; p++)
            gload16(Bg + (size_t)(p * 32) * Kst + kt, &Bs[(srow + p * 32) * 8 + sc]);
        asm volatile("s_waitcnt vmcnt(0)" ::: "memory");
        __syncthreads();
        #pragma unroll
        for (int kk = 0; kk < 2; kk++) {
            bf16x8 af[4], bfr[NFRAG];
            int c = kk * 4 + g;
            #pragma unroll
            for (int m = 0; m < 4; m++)
                af[m] = __builtin_bit_cast(bf16x8, As[(wrow + m * 16 + lrow) * 8 + c]);
            #pragma unroll
            for (int n = 0; n < NFRAG; n++)
                bfr[n] = __builtin_bit_cast(bf16x8, Bs[(wcol + n * 16 + lrow) * 8 + c]);
            #pragma unroll
            for (int m = 0; m < 4; m++)
                #pragma unroll
                for (int n = 0; n < NFRAG; n++)
                    acc[m][n] = MFMA16(af[m], bfr[n], acc[m][n]);
        }
    }

    for (int n = 0; n < NFRAG; n++) {
        int col = bn + wcol + n * 16 + lrow;
        float bval = bias ? bias[col] : 0.f;
        for (int m = 0; m < 4; m++) {
            int row0 = bm + wrow + m * 16 + g * 4;
            for (int r = 0; r < 4; r++) {
                int row = row0 + r;
                float v = acc[m][n][r] + bval;
                if (RELU) v = fmaxf(v, 0.f);
                if (RES) v += res[(size_t)row * N + col];
                if (RES2) v += res2[(size_t)row * N + col];
                if (WF32) Cf[(size_t)row * N + col] = v;
                if (WBF16) Cb[(size_t)row * N + col] = (__bf16)v;
            }
        }
    }
}

// ---------------------------------------------------------------------------
// attn_flash v5 (+ P zero-fill backfill blocks).
// Flash blocks [0,512): 64 q rows (4 waves x 16), one head. All waves share
// the SAME kv tile range (ntiles = b/2+1); K and V tiles staged ONCE per
// block in LDS via global_load_lds (pre-swizzled source, XOR-swz read).
// Each wave owns its 16 rows end-to-end: no cross-wave combines.
// Defer-max softmax; mask only on the last tile.
// Blocks [512, 2432): zero-fill of P's strict upper-triangle 128x128 tiles.
// ---------------------------------------------------------------------------
__global__ __launch_bounds__(256, 3)
void attn_flash(const __bf16* __restrict__ qkv, const __bf16* __restrict__ vt,
                float* __restrict__ Obuf, __bf16* __restrict__ ctx,
                float* __restrict__ P)
{
    __shared__ char Ks[16384];      // [128 kv][64 dk] bf16, chunk-swizzled
    __shared__ char Vs[16384];      // [64 d][128 kv] bf16, chunk-swizzled
    __shared__ char Plds[4][4096];  // per-wave P stage
    const int tid = threadIdx.x;

    if (blockIdx.x >= 512) {
        // ---- zero-fill kt>qt tiles ----
        int id = blockIdx.x - 512;          // [0,1920)
        int h = id / 120;
        int pr = id - h * 120;
        int qt = 0, acc = 0;
        while (pr >= acc + 15 - qt) { acc += 15 - qt; qt++; }
        int kt = qt + 1 + (pr - acc);
        f32x4 z = {0.f, 0.f, 0.f, 0.f};
        float* base = P + (size_t)h * S_LEN * S_LEN + (size_t)(qt * 128) * S_LEN + kt * 128;
        #pragma unroll
        for (int i = 0; i < 16; i++) {
            int idx = i * 256 + tid;
            int row = idx >> 5, c = idx & 31;
            __builtin_nontemporal_store(z, (f32x4*)(base + (size_t)row * S_LEN + c * 4));
        }
        return;
    }

    const int lane = tid & 63;
    const int w = tid >> 6;
    const int lrow = lane & 15;
    const int g = lane >> 4;
    const int h = blockIdx.x & 15;
    const int b = 31 - ((int)blockIdx.x >> 4);   // heavy-first
    const int qg = b * 64 + w * 16 + lrow;       // this lane's q row
    const int ntiles = (b >> 1) + 1;             // uniform across block
    const float c1 = 0.18033688f;                // 0.125 * log2(e)
    const __bf16* ksec = qkv + 1024;
    char* plB = Plds[w];

    bf16x8 qf[2];
    qf[0] = *(const bf16x8*)(qkv + (size_t)qg * 3072 + h * DK + g * 8);
    qf[1] = *(const bf16x8*)(qkv + (size_t)qg * 3072 + h * DK + 32 + g * 8);

    float m2 = -1e30f, l = 0.f;
    f32x4 acc2[4];
    #pragma unroll
    for (int i = 0; i < 4; i++) acc2[i] = (f32x4){0.f, 0.f, 0.f, 0.f};

    // staging coordinates (LDS byte = w*1024 + p*4096 + lane*16, linear)
    const int sKrow = (w << 3) + (lane >> 3);    // + p*32
    const int sKch = lane & 7;
    const int sVrow = (w << 2) + (lane >> 4);    // + p*16
    const int sVch = lane & 15;
    char* const KsW = Ks + w * 1024;
    char* const VsW = Vs + w * 1024;

    for (int kt = 0; kt < ntiles; kt++) {
        // ---- stage K,V tile (pre-swizzled source -> linear LDS) ----
        #pragma unroll
        for (int p = 0; p < 4; p++) {
            int row = sKrow + p * 32;
            int ch = sKch ^ (row & 7);
            gload16(ksec + (size_t)(kt * 128 + row) * 3072 + h * DK + ch * 8,
                    KsW + p * 4096 + lane * 16);
        }
        #pragma unroll
        for (int p = 0; p < 4; p++) {
            int row = sVrow + p * 16;
            int ch = sVch ^ (row & 7);
            gload16(vt + (size_t)(h * DK + row) * S_LEN + kt * 128 + ch * 8,
                    VsW + p * 4096 + lane * 16);
        }
        asm volatile("s_waitcnt vmcnt(0)" ::: "memory");
        __syncthreads();

        // ---- QK^T from LDS ----
        f32x4 acc[8];
        #pragma unroll
        for (int mf = 0; mf < 8; mf++) acc[mf] = (f32x4){0.f, 0.f, 0.f, 0.f};
        #pragma unroll
        for (int kk = 0; kk < 2; kk++)
            #pragma unroll
            for (int mf = 0; mf < 8; mf++) {
                int row = mf * 16 + lrow;
                bf16x8 kf = *(const bf16x8*)(Ks + row * 128 + (((kk * 4 + g) ^ (row & 7)) << 4));
                acc[mf] = MFMA16(kf, qf[kk], acc[mf]);
            }

        // ---- scores + defer-max softmax ----
        float s[8][4];
        float tmx = -1e30f;
        const bool lastT = (kt == ntiles - 1);
        #pragma unroll
        for (int mf = 0; mf < 8; mf++) {
            int kvb = kt * 128 + mf * 16 + g * 4;
            #pragma unroll
            for (int r = 0; r < 4; r++) {
                float sv = acc[mf][r] * c1;
                if (lastT) sv = (kvb + r <= qg) ? sv : -1e30f;
                s[mf][r] = sv;
                tmx = fmaxf(tmx, sv);
            }
        }
        if (!__all((int)(tmx <= m2 + 6.f))) {
            float tm = fmaxf(tmx, __shfl_xor(tmx, 16));
            tm = fmaxf(tm, __shfl_xor(tm, 32));
            float nm = fmaxf(m2, tm);
            float sc = exp2f(m2 - nm);
            l *= sc;
            #pragma unroll
            for (int md = 0; md < 4; md++) acc2[md] *= sc;
            m2 = nm;
        }
        float sum = 0.f;
        #pragma unroll
        for (int mf = 0; mf < 8; mf++) {
            float p0 = exp2f(s[mf][0] - m2);
            float p1 = exp2f(s[mf][1] - m2);
            float p2 = exp2f(s[mf][2] - m2);
            float p3 = exp2f(s[mf][3] - m2);
            sum += (p0 + p1) + (p2 + p3);
            uint2 pk;
            pk.x = pack_bf16x2(p0, p1);
            pk.y = pack_bf16x2(p2, p3);
            *(uint2*)(plB + ((lrow * 256 + mf * 32 + g * 8) ^ ((lrow & 7) << 4))) = pk;
        }
        l += sum;

        // ---- PV from LDS ----
        #pragma unroll
        for (int ks = 0; ks < 4; ks++) {
            bf16x8 pf = *(bf16x8*)(plB + ((lrow * 256 + ks * 64 + g * 16) ^ ((lrow & 7) << 4)));
            #pragma unroll
            for (int md = 0; md < 4; md++) {
                int row = md * 16 + lrow;
                bf16x8 vf = *(const bf16x8*)(Vs + row * 256 + (((ks * 4 + g) ^ (row & 7)) << 4));
                acc2[md] = MFMA16(vf, pf, acc2[md]);
            }
        }
        __syncthreads();   // all reads done before next stage overwrites
    }

    // ---- finalize: cross-g l sum (m2 uniform), write Obuf + ctx ----
    l += __shfl_xor(l, 16);
    l += __shfl_xor(l, 32);
    float li = 1.f / l;
    if (lane < 16)
        Obuf[h * S_LEN + qg] = -m2 - log2f(l);
    #pragma unroll
    for (int md = 0; md < 4; md++) {
        uint2 pk;
        pk.x = pack_bf16x2(acc2[md][0] * li, acc2[md][1] * li);
        pk.y = pack_bf16x2(acc2[md][2] * li, acc2[md][3] * li);
        *(uint2*)(ctx + (size_t)qg * D_MOD + h * DK + md * 16 + g * 4) = pk;
    }
}

// ---------------------------------------------------------------------------
// ff1_pwrite: heterogeneous. Blocks [0,512): ff1 GEMM. Blocks [512,2688):
// P materialize for kt<=qt tiles (QK^T + exp2 with Obuf, nontemporal stores).
// ---------------------------------------------------------------------------
__global__ __launch_bounds__(256)
void ff1_pwrite(const __bf16* __restrict__ A, const __bf16* __restrict__ BT,
                const float* __restrict__ bias, __bf16* __restrict__ Cb,
                const __bf16* __restrict__ qkv, const float* __restrict__ Obuf,
                float* __restrict__ P)
{
    __shared__ uint4 As[128 * 8];
    __shared__ uint4 Bs[128 * 8];
    const int tid = threadIdx.x;
    const int lane = tid & 63;
    const int w = tid >> 6;
    const int lrow = lane & 15;
    const int g = lane >> 4;

    if (blockIdx.x < 512) {
        // ---------------- ff1 GEMM: M=2048 N=4096 K=1024 ----------------
        const int bid = blockIdx.x;
        const int bm = (bid >> 5) * 128;
        const int bn = (bid & 31) * 128;
        const int wrow = (w >> 1) * 64;
        const int wcol = (w & 1) * 64;
        f32x4 acc[4][4];
        for (int m = 0; m < 4; m++)
            for (int n = 0; n < 4; n++)
                acc[m][n] = (f32x4){0.f, 0.f, 0.f, 0.f};
        const int srow = tid >> 3;
        const int sc = tid & 7;
        const __bf16* Ag = A + (size_t)(bm + srow) * 1024 + sc * 8;
        const __bf16* Bg = BT + (size_t)(bn + srow) * 1024 + sc * 8;
        for (int kt = 0; kt < 1024; kt += 64) {
            __syncthreads();
            #pragma unroll
            for (int p = 0; p < 4; p++)
                gload16(Ag + (size_t)(p * 32) * 1024 + kt, &As[(srow + p * 32) * 8 + sc]);
            #pragma unroll
            for (int p = 0; p < 4; p++)
                gload16(Bg + (size_t)(p * 32) * 1024 + kt, &Bs[(srow + p * 32) * 8 + sc]);
            asm volatile("s_waitcnt vmcnt(0)" ::: "memory");
            __syncthreads();
            #pragma unroll
            for (int kk = 0; kk < 2; kk++) {
                bf16x8 af[4], bfr[4];
                int c = kk * 4 + g;
                #pragma unroll
                for (int m = 0; m < 4; m++)
                    af[m] = __builtin_bit_cast(bf16x8, As[(wrow + m * 16 + lrow) * 8 + c]);
                #pragma unroll
                for (int n = 0; n < 4; n++)
                    bfr[n] = __builtin_bit_cast(bf16x8, Bs[(wcol + n * 16 + lrow) * 8 + c]);
                #pragma unroll
                for (int m = 0; m < 4; m++)
                    #pragma unroll
                    for (int n = 0; n < 4; n++)
                        acc[m][n] = MFMA16(af[m], bfr[n], acc[m][n]);
            }
        }
        for (int n = 0; n < 4; n++) {
            int col = bn + wcol + n * 16 + lrow;
            float bval = bias[col];
            for (int m = 0; m < 4; m++) {
                int row0 = bm + wrow + m * 16 + g * 4;
                for (int r = 0; r < 4; r++) {
                    float v = fmaxf(acc[m][n][r] + bval, 0.f);
                    Cb[(size_t)(row0 + r) * D_FF + col] = (__bf16)v;
                }
            }
        }
        return;
    }

    // ---------------- P materialization (kt <= qt only) ----------------
    const int id2 = blockIdx.x - 512;   // [0, 2176)
    const int h = id2 / 136;
    int tt = id2 - h * 136;
    int qt = 0;
    while (tt > qt) { tt -= qt + 1; qt++; }
    const int kt = tt;
    const size_t Pb = (size_t)h * S_LEN * S_LEN;

    const float c1 = 0.18033688f;
    const __bf16* ksec = qkv + 1024;

    bf16x8 qfr[2][2];
    #pragma unroll
    for (int qq = 0; qq < 2; qq++)
        #pragma unroll
        for (int kk = 0; kk < 2; kk++)
            qfr[qq][kk] = *(const bf16x8*)(qkv +
                (size_t)(qt * 128 + w * 32 + qq * 16 + lrow) * 3072 + h * DK + kk * 32 + g * 8);

    f32x4 acc[2][8];
    #pragma unroll
    for (int qq = 0; qq < 2; qq++)
        #pragma unroll
        for (int mf = 0; mf < 8; mf++) acc[qq][mf] = (f32x4){0.f, 0.f, 0.f, 0.f};
    #pragma unroll
    for (int kk = 0; kk < 2; kk++) {
        #pragma unroll
        for (int mf = 0; mf < 8; mf++) {
            bf16x8 kf = *(const bf16x8*)(ksec +
                (size_t)(kt * 128 + mf * 16 + lrow) * 3072 + h * DK + kk * 32 + g * 8);
            acc[0][mf] = MFMA16(kf, qfr[0][kk], acc[0][mf]);
            acc[1][mf] = MFMA16(kf, qfr[1][kk], acc[1][mf]);
        }
    }

    #pragma unroll
    for (int qq = 0; qq < 2; qq++) {
        int q = qt * 128 + w * 32 + qq * 16 + lrow;
        float offv = Obuf[h * S_LEN + q];
        float* prow = P + Pb + (size_t)q * S_LEN;
        if (kt == qt) {
            #pragma unroll
            for (int mf = 0; mf < 8; mf++) {
                int kvb = kt * 128 + mf * 16 + g * 4;
                f32x4 st;
                st[0] = (kvb + 0 <= q) ? exp2f(acc[qq][mf][0] * c1 + offv) : 0.f;
                st[1] = (kvb + 1 <= q) ? exp2f(acc[qq][mf][1] * c1 + offv) : 0.f;
                st[2] = (kvb + 2 <= q) ? exp2f(acc[qq][mf][2] * c1 + offv) : 0.f;
                st[3] = (kvb + 3 <= q) ? exp2f(acc[qq][mf][3] * c1 + offv) : 0.f;
                __builtin_nontemporal_store(st, (f32x4*)(prow + kvb));
            }
        } else {
            #pragma unroll
            for (int mf = 0; mf < 8; mf++) {
                int kvb = kt * 128 + mf * 16 + g * 4;
                f32x4 st;
                st[0] = exp2f(acc[qq][mf][0] * c1 + offv);
                st[1] = exp2f(acc[qq][mf][1] * c1 + offv);
                st[2] = exp2f(acc[qq][mf][2] * c1 + offv);
                st[3] = exp2f(acc[qq][mf][3] * c1 + offv);
                __builtin_nontemporal_store(st, (f32x4*)(prow + kvb));
            }
        }
    }
}

// ---------------------------------------------------------------------------
extern "C" void kernel_launch(void* const* d_in, const int* in_sizes, int n_in,
                              void* d_out, int out_size, void* d_ws, size_t ws_size,
                              hipStream_t stream)
{
    const float* x     = (const float*)d_in[0];
    const float* g1    = (const float*)d_in[1];
    const float* beta1 = (const float*)d_in[2];
    const float* W_in  = (const float*)d_in[3];
    const float* b_in  = (const float*)d_in[4];
    const float* Wq    = (const float*)d_in[5];
    const float* bq    = (const float*)d_in[6];
    const float* Wk    = (const float*)d_in[7];
    const float* bk    = (const float*)d_in[8];
    const float* Wv    = (const float*)d_in[9];
    const float* bv    = (const float*)d_in[10];
    const float* Wo    = (const float*)d_in[11];
    const float* bo    = (const float*)d_in[12];
    const float* W2    = (const float*)d_in[13];
    const float* b2    = (const float*)d_in[14];
    const float* g2    = (const float*)d_in[15];
    const float* beta2 = (const float*)d_in[16];
    const float* Wf1   = (const float*)d_in[17];
    const float* bf1   = (const float*)d_in[18];
    const float* Wf2   = (const float*)d_in[19];
    const float* bf2   = (const float*)d_in[20];

    float* outp = (float*)d_out;                    // [2048][1024]
    float* Pout = outp + (size_t)S_LEN * D_MOD;     // [16][2048][2048]

    char* p = (char*)d_ws;
    auto alloc = [&](size_t b) -> void* {
        void* r = (void*)p;
        p += (b + 255) & ~(size_t)255;
        return r;
    };
    __bf16* WqkvT    = (__bf16*)alloc((size_t)3072 * 1024 * 2);
    __bf16* W2T      = (__bf16*)alloc((size_t)1024 * 1024 * 2);
    __bf16* Wf1T     = (__bf16*)alloc((size_t)D_FF * D_MOD * 2);
    __bf16* Wf2T     = (__bf16*)alloc((size_t)D_MOD * D_FF * 2);
    __bf16* WqkvCT   = (__bf16*)alloc((size_t)3072 * 1024 * 2);
    __bf16* WcombT   = (__bf16*)alloc((size_t)1024 * 1024 * 2);
    float*  bqkv     = (float*)alloc((size_t)3072 * 4);
    float*  bcomb    = (float*)alloc((size_t)1024 * 4);
    float*  biaspart = (float*)alloc((size_t)8 * 4096 * 4);
    __bf16* xn_b     = (__bf16*)alloc((size_t)S_LEN * D_MOD * 2);
    __bf16* qkv_b    = (__bf16*)alloc((size_t)S_LEN * 3072 * 2);
    __bf16* VT       = (__bf16*)alloc((size_t)N_HEADS * DK * S_LEN * 2);
    __bf16* ctx_b    = (__bf16*)alloc((size_t)S_LEN * D_MOD * 2);
    float*  part1f   = (float*)alloc((size_t)S_LEN * D_MOD * 4);
    float*  norm2f   = (float*)alloc((size_t)S_LEN * D_MOD * 4);
    __bf16* norm2b   = (__bf16*)alloc((size_t)S_LEN * D_MOD * 2);
    __bf16* ff1_b    = (__bf16*)alloc((size_t)S_LEN * D_FF * 2);
    float*  Obuf     = (float*)alloc((size_t)N_HEADS * S_LEN * 4);
    // aliases (lifetimes disjoint, stream-ordered):
    __bf16* Win_b  = (__bf16*)part1f;   // weight staging before part1 GEMM
    __bf16* Wo_b   = (__bf16*)norm2f;   // weight staging before ln2
    float*  ffpart = part1f;            // split-K partial after ln2 consumed part1f

    dim3 blk(256);

    // --- weight prep ---
    transpose_all<<<dim3(12288), blk, 0, stream>>>(Wq, Wk, Wv, W2, Wf1, Wf2,
                                                   WqkvT, W2T, Wf1T, Wf2T);
    convert_all<<<dim3(2048), blk, 0, stream>>>(W_in, Wo, Win_b, Wo_b);
    bias_stage1<<<dim3(16, 8), blk, 0, stream>>>(b_in, bo, Wq, Wk, Wv, W2, biaspart);
    bias_stage2<<<dim3(16), blk, 0, stream>>>(biaspart, bq, bk, bv, b2, bqkv, bcomb);

    // (Win·Wqkv)^T and (Wo·W2)^T
    gemm_kernel<64, false, false, false, false, true><<<dim3(16, 24), blk, 0, stream>>>(
        WqkvT, Win_b, nullptr, nullptr, nullptr, nullptr, WqkvCT, 3072, 1024, 1024, 1024);
    gemm_kernel<64, false, false, false, false, true><<<dim3(16, 8), blk, 0, stream>>>(
        W2T, Wo_b, nullptr, nullptr, nullptr, nullptr, WcombT, 1024, 1024, 1024, 1024);

    // --- forward ---
    ln_kernel<<<S_LEN, blk, 0, stream>>>(x, g1, beta1, xn_b, nullptr);

    gemm_kernel<128, false, false, false, false, true><<<dim3(24, 16), blk, 0, stream>>>(
        xn_b, WqkvCT, bqkv, nullptr, nullptr, nullptr, qkv_b, 2048, 3072, 1024, 1024);

    vhead_transpose<<<dim3(64, 2, 16), blk, 0, stream>>>(qkv_b + 2048, VT);

    // flash attention + P upper-triangle zero-fill backfill
    attn_flash<<<dim3(512 + 1920), blk, 0, stream>>>(qkv_b, VT, Obuf, ctx_b, Pout);

    gemm_kernel<64, false, true, false, true, false><<<dim3(16, 16), blk, 0, stream>>>(
        ctx_b, WcombT, bcomb, x, nullptr, part1f, nullptr, 2048, 1024, 1024, 1024);

    ln_kernel<<<S_LEN, blk, 0, stream>>>(part1f, g2, beta2, norm2b, norm2f);

    // ff1 GEMM + P materialization (kt<=qt), one heterogeneous launch
    ff1_pwrite<<<dim3(512 + 2176), blk, 0, stream>>>(
        norm2b, Wf1T, bf1, ff1_b, qkv_b, Obuf, Pout);

    // ff2 split-K: K half 1 -> ffpart (f32), half 2 adds norm2 + ffpart + bias
    gemm_kernel<64, false, false, false, true, false><<<dim3(16, 16), blk, 0, stream>>>(
        ff1_b, Wf2T, nullptr, nullptr, nullptr, ffpart, nullptr, 2048, 1024, 4096, 2048);
    gemm_kernel<64, false, true, true, true, false><<<dim3(16, 16), blk, 0, stream>>>(
        ff1_b + 2048, Wf2T + 2048, bf2, norm2f, ffpart, outp, nullptr, 2048, 1024, 4096, 2048);
}

// Round 11
// 261.765 us; speedup vs baseline: 1.6429x; 1.1921x over previous
//
#include <hip/hip_runtime.h>
#include <hip/hip_bf16.h>
#include <cstdint>

#define S_LEN 2048
#define D_MOD 1024
#define N_HEADS 16
#define DK 64
#define D_FF 4096

typedef __bf16 bf16x8 __attribute__((ext_vector_type(8)));
typedef float f32x4 __attribute__((ext_vector_type(4)));

#define MFMA16(a, b, c) __builtin_amdgcn_mfma_f32_16x16x32_bf16((a), (b), (c), 0, 0, 0)

__device__ inline unsigned pack_bf16x2(float a, float b)
{
    unsigned short ua = __builtin_bit_cast(unsigned short, (__bf16)a);
    unsigned short ub = __builtin_bit_cast(unsigned short, (__bf16)b);
    return (unsigned)ua | ((unsigned)ub << 16);
}

// async global->LDS, 16B per lane; LDS dest must equal waveBase + lane*16
__device__ inline void gload16(const void* g, void* l)
{
    __builtin_amdgcn_global_load_lds(
        (const __attribute__((address_space(1))) unsigned int*)g,
        (__attribute__((address_space(3))) unsigned int*)l, 16, 0, 0);
}

// ---------------------------------------------------------------------------
// Shared GEMM block body: C[.][N] tile at (bx,by) = A[M][Kst] * BT[N][Kst]
// ---------------------------------------------------------------------------
template<int BN, bool RELU, bool RES, bool RES2, bool WF32, bool WBF16>
__device__ __forceinline__
void gemm_dev(const __bf16* __restrict__ A, const __bf16* __restrict__ BT,
              const float* __restrict__ bias, const float* __restrict__ res,
              const float* __restrict__ res2,
              float* __restrict__ Cf, __bf16* __restrict__ Cb,
              int N, int Kst, int Klp, int bx, int by,
              uint4* As, uint4* Bs)
{
    constexpr int NFRAG = BN / 32;
    const int tid = threadIdx.x;
    const int lane = tid & 63;
    const int w = tid >> 6;
    const int lrow = lane & 15;
    const int g = lane >> 4;
    const int bm = by * 128;
    const int bn = bx * BN;
    const int wrow = (w >> 1) * 64;
    const int wcol = (w & 1) * (BN / 2);

    f32x4 acc[4][NFRAG];
    for (int m = 0; m < 4; m++)
        for (int n = 0; n < NFRAG; n++)
            acc[m][n] = (f32x4){0.f, 0.f, 0.f, 0.f};

    const int srow = tid >> 3;
    const int sc = tid & 7;
    const __bf16* Ag = A + (size_t)(bm + srow) * Kst + sc * 8;
    const __bf16* Bg = BT + (size_t)(bn + srow) * Kst + sc * 8;

    for (int kt = 0; kt < Klp; kt += 64) {
        __syncthreads();
        #pragma unroll
        for (int p = 0; p < 4; p++)
            gload16(Ag + (size_t)(p * 32) * Kst + kt, &As[(srow + p * 32) * 8 + sc]);
        #pragma unroll
        for (int p = 0; p < NFRAG; p++)
            gload16(Bg + (size_t)(p * 32) * Kst + kt, &Bs[(srow + p * 32) * 8 + sc]);
        asm volatile("s_waitcnt vmcnt(0)" ::: "memory");
        __syncthreads();
        #pragma unroll
        for (int kk = 0; kk < 2; kk++) {
            bf16x8 af[4], bfr[NFRAG];
            int c = kk * 4 + g;
            #pragma unroll
            for (int m = 0; m < 4; m++)
                af[m] = __builtin_bit_cast(bf16x8, As[(wrow + m * 16 + lrow) * 8 + c]);
            #pragma unroll
            for (int n = 0; n < NFRAG; n++)
                bfr[n] = __builtin_bit_cast(bf16x8, Bs[(wcol + n * 16 + lrow) * 8 + c]);
            #pragma unroll
            for (int m = 0; m < 4; m++)
                #pragma unroll
                for (int n = 0; n < NFRAG; n++)
                    acc[m][n] = MFMA16(af[m], bfr[n], acc[m][n]);
        }
    }

    for (int n = 0; n < NFRAG; n++) {
        int col = bn + wcol + n * 16 + lrow;
        float bval = bias ? bias[col] : 0.f;
        for (int m = 0; m < 4; m++) {
            int row0 = bm + wrow + m * 16 + g * 4;
            for (int r = 0; r < 4; r++) {
                int row = row0 + r;
                float v = acc[m][n][r] + bval;
                if (RELU) v = fmaxf(v, 0.f);
                if (RES) v += res[(size_t)row * N + col];
                if (RES2) v += res2[(size_t)row * N + col];
                if (WF32) Cf[(size_t)row * N + col] = v;
                if (WBF16) Cb[(size_t)row * N + col] = (__bf16)v;
            }
        }
    }
}

// ---------------------------------------------------------------------------
// LayerNorm row body
// ---------------------------------------------------------------------------
__device__ __forceinline__
void ln_row(int row, const float* __restrict__ x, const float* __restrict__ gamma,
            const float* __restrict__ beta, __bf16* __restrict__ outb,
            float* __restrict__ outf, float* red)
{
    int tid = threadIdx.x;
    const float4 v = ((const float4*)(x + (size_t)row * D_MOD))[tid];
    float s = v.x + v.y + v.z + v.w;
    float sq = v.x * v.x + v.y * v.y + v.z * v.z + v.w * v.w;
    for (int off = 32; off; off >>= 1) {
        s += __shfl_down(s, off);
        sq += __shfl_down(sq, off);
    }
    int wid = tid >> 6;
    if ((tid & 63) == 0) { red[wid] = s; red[wid + 4] = sq; }
    __syncthreads();
    s = red[0] + red[1] + red[2] + red[3];
    sq = red[4] + red[5] + red[6] + red[7];
    float mean = s * (1.f / D_MOD);
    float var = fmaxf(sq * (1.f / D_MOD) - mean * mean, 0.f);
    float inv = 1.f / (sqrtf(var) + 1e-6f);
    float4 gv = ((const float4*)gamma)[tid];
    float4 bv = ((const float4*)beta)[tid];
    float y0 = gv.x * ((v.x - mean) * inv) + bv.x;
    float y1 = gv.y * ((v.y - mean) * inv) + bv.y;
    float y2 = gv.z * ((v.z - mean) * inv) + bv.z;
    float y3 = gv.w * ((v.w - mean) * inv) + bv.w;
    uint2 pk;
    pk.x = pack_bf16x2(y0, y1);
    pk.y = pack_bf16x2(y2, y3);
    ((uint2*)(outb + (size_t)row * D_MOD))[tid] = pk;
    if (outf) {
        float4 o = {y0, y1, y2, y3};
        ((float4*)(outf + (size_t)row * D_MOD))[tid] = o;
    }
}

// ---------------------------------------------------------------------------
// P tile write body (kt <= qt), swapped mfma(K,Q), nontemporal f32x4 stores
// ---------------------------------------------------------------------------
__device__ __forceinline__
void pwrite_tile(const __bf16* __restrict__ qkv, const float* __restrict__ Obuf,
                 float* __restrict__ P, int h, int qt, int kt)
{
    const int tid = threadIdx.x;
    const int lane = tid & 63;
    const int w = tid >> 6;
    const int lrow = lane & 15;
    const int g = lane >> 4;
    const float c1 = 0.18033688f;
    const __bf16* ksec = qkv + 1024;
    const size_t Pb = (size_t)h * S_LEN * S_LEN;

    bf16x8 qfr[2][2];
    #pragma unroll
    for (int qq = 0; qq < 2; qq++)
        #pragma unroll
        for (int kk = 0; kk < 2; kk++)
            qfr[qq][kk] = *(const bf16x8*)(qkv +
                (size_t)(qt * 128 + w * 32 + qq * 16 + lrow) * 3072 + h * DK + kk * 32 + g * 8);

    f32x4 acc[2][8];
    #pragma unroll
    for (int qq = 0; qq < 2; qq++)
        #pragma unroll
        for (int mf = 0; mf < 8; mf++) acc[qq][mf] = (f32x4){0.f, 0.f, 0.f, 0.f};
    #pragma unroll
    for (int kk = 0; kk < 2; kk++) {
        #pragma unroll
        for (int mf = 0; mf < 8; mf++) {
            bf16x8 kf = *(const bf16x8*)(ksec +
                (size_t)(kt * 128 + mf * 16 + lrow) * 3072 + h * DK + kk * 32 + g * 8);
            acc[0][mf] = MFMA16(kf, qfr[0][kk], acc[0][mf]);
            acc[1][mf] = MFMA16(kf, qfr[1][kk], acc[1][mf]);
        }
    }

    #pragma unroll
    for (int qq = 0; qq < 2; qq++) {
        int q = qt * 128 + w * 32 + qq * 16 + lrow;
        float offv = Obuf[h * S_LEN + q];
        float* prow = P + Pb + (size_t)q * S_LEN;
        if (kt == qt) {
            #pragma unroll
            for (int mf = 0; mf < 8; mf++) {
                int kvb = kt * 128 + mf * 16 + g * 4;
                f32x4 st;
                st[0] = (kvb + 0 <= q) ? exp2f(acc[qq][mf][0] * c1 + offv) : 0.f;
                st[1] = (kvb + 1 <= q) ? exp2f(acc[qq][mf][1] * c1 + offv) : 0.f;
                st[2] = (kvb + 2 <= q) ? exp2f(acc[qq][mf][2] * c1 + offv) : 0.f;
                st[3] = (kvb + 3 <= q) ? exp2f(acc[qq][mf][3] * c1 + offv) : 0.f;
                __builtin_nontemporal_store(st, (f32x4*)(prow + kvb));
            }
        } else {
            #pragma unroll
            for (int mf = 0; mf < 8; mf++) {
                int kvb = kt * 128 + mf * 16 + g * 4;
                f32x4 st;
                st[0] = exp2f(acc[qq][mf][0] * c1 + offv);
                st[1] = exp2f(acc[qq][mf][1] * c1 + offv);
                st[2] = exp2f(acc[qq][mf][2] * c1 + offv);
                st[3] = exp2f(acc[qq][mf][3] * c1 + offv);
                __builtin_nontemporal_store(st, (f32x4*)(prow + kvb));
            }
        }
    }
}

// ---------------------------------------------------------------------------
// prep1: blocks [0,12288) weight transposes; [12288,14336) plain converts;
// [14336,14464) bias_stage1 partials. All independent.
// ---------------------------------------------------------------------------
__global__ __launch_bounds__(256)
void prep1(const float* __restrict__ Wq, const float* __restrict__ Wk,
           const float* __restrict__ Wv, const float* __restrict__ W2,
           const float* __restrict__ Wf1, const float* __restrict__ Wf2,
           const float* __restrict__ W_in, const float* __restrict__ Wo,
           const float* __restrict__ b_in, const float* __restrict__ bo,
           __bf16* __restrict__ WqkvT, __bf16* __restrict__ W2T,
           __bf16* __restrict__ Wf1T, __bf16* __restrict__ Wf2T,
           __bf16* __restrict__ Win_b, __bf16* __restrict__ Wo_b,
           float* __restrict__ part)
{
    __shared__ float tile[32][33];
    int id = blockIdx.x;
    int tid = threadIdx.x;
    if (id < 12288) {
        const float* W; __bf16* WT; int K, N, n0, k0;
        if (id < 4096) {
            int m = id >> 10; id &= 1023;
            K = 1024; N = 1024;
            n0 = (id & 31) * 32; k0 = (id >> 5) * 32;
            W = m == 0 ? Wq : (m == 1 ? Wk : (m == 2 ? Wv : W2));
            WT = m == 3 ? W2T : WqkvT + (size_t)m * 1024 * 1024;
        } else if (id < 8192) {
            id -= 4096;
            K = 1024; N = 4096;
            n0 = (id & 127) * 32; k0 = (id >> 7) * 32;
            W = Wf1; WT = Wf1T;
        } else {
            id -= 8192;
            K = 4096; N = 1024;
            n0 = (id & 31) * 32; k0 = (id >> 5) * 32;
            W = Wf2; WT = Wf2T;
        }
        int tx = tid & 31, ty = tid >> 5;
        for (int i = 0; i < 4; i++)
            tile[ty + i * 8][tx] = W[(size_t)(k0 + ty + i * 8) * N + n0 + tx];
        __syncthreads();
        for (int i = 0; i < 4; i++)
            WT[(size_t)(n0 + ty + i * 8) * K + k0 + tx] = (__bf16)tile[tx][ty + i * 8];
        return;
    }
    id -= 12288;
    if (id < 2048) {
        const float* W = id < 1024 ? W_in : Wo;
        __bf16* o = id < 1024 ? Win_b : Wo_b;
        int i = (id & 1023) * 256 + tid;
        float4 v = ((const float4*)W)[i];
        uint2 pk;
        pk.x = pack_bf16x2(v.x, v.y);
        pk.y = pack_bf16x2(v.z, v.w);
        ((uint2*)o)[i] = pk;
        return;
    }
    id -= 2048;
    {   // bias_stage1: id in [0,128): bx = id&15, kc = id>>4
        int n = (id & 15) * 256 + tid;
        int kc = id >> 4;
        int sel = n >> 10, col = n & 1023;
        const float* W = sel == 0 ? Wq : (sel == 1 ? Wk : (sel == 2 ? Wv : W2));
        const float* src = sel < 3 ? b_in : bo;
        float s = 0.f;
        for (int k = kc * 128; k < kc * 128 + 128; k++)
            s += src[k] * W[(size_t)k * 1024 + col];
        part[kc * 4096 + n] = s;
    }
}

// ---------------------------------------------------------------------------
// prep2: [0,384) WqkvCT gemm; [384,512) WcombT gemm; [512,528) bias_stage2;
// [528,2576) LN1 rows.
// ---------------------------------------------------------------------------
__global__ __launch_bounds__(256, 2)
void prep2(const __bf16* __restrict__ WqkvT, const __bf16* __restrict__ Win_b,
           __bf16* __restrict__ WqkvCT,
           const __bf16* __restrict__ W2T, const __bf16* __restrict__ Wo_b,
           __bf16* __restrict__ WcombT,
           const float* __restrict__ part,
           const float* __restrict__ bq, const float* __restrict__ bk,
           const float* __restrict__ bv, const float* __restrict__ b2,
           float* __restrict__ bqkv, float* __restrict__ bcomb,
           const float* __restrict__ x, const float* __restrict__ g1,
           const float* __restrict__ beta1, __bf16* __restrict__ xn_b)
{
    __shared__ uint4 As[128 * 8];
    __shared__ uint4 Bs[64 * 8];
    int id = blockIdx.x;
    int tid = threadIdx.x;
    if (id < 384) {
        gemm_dev<64, false, false, false, false, true>(
            WqkvT, Win_b, nullptr, nullptr, nullptr, nullptr, WqkvCT,
            1024, 1024, 1024, id & 15, id >> 4, As, Bs);
        return;
    }
    id -= 384;
    if (id < 128) {
        gemm_dev<64, false, false, false, false, true>(
            W2T, Wo_b, nullptr, nullptr, nullptr, nullptr, WcombT,
            1024, 1024, 1024, id & 15, id >> 4, As, Bs);
        return;
    }
    id -= 128;
    if (id < 16) {
        int n = id * 256 + tid;
        int sel = n >> 10, col = n & 1023;
        float s = sel == 0 ? bq[col] : (sel == 1 ? bk[col] : (sel == 2 ? bv[col] : b2[col]));
        for (int kc = 0; kc < 8; kc++) s += part[kc * 4096 + n];
        if (n < 3072) bqkv[n] = s; else bcomb[col] = s;
        return;
    }
    id -= 16;
    ln_row(id, x, g1, beta1, xn_b, nullptr, (float*)As);
}

// ---------------------------------------------------------------------------
// Standalone GEMM kernel (qkv / part1)
// ---------------------------------------------------------------------------
template<int BN, bool RELU, bool RES, bool RES2, bool WF32, bool WBF16>
__global__ __launch_bounds__(256, 2)
void gemm_kernel(const __bf16* __restrict__ A, const __bf16* __restrict__ BT,
                 const float* __restrict__ bias, const float* __restrict__ res,
                 const float* __restrict__ res2,
                 float* __restrict__ Cf, __bf16* __restrict__ Cb,
                 int N, int Kst, int Klp)
{
    __shared__ uint4 As[128 * 8];
    __shared__ uint4 Bs[BN * 8];
    gemm_dev<BN, RELU, RES, RES2, WF32, WBF16>(
        A, BT, bias, res, res2, Cf, Cb, N, Kst, Klp,
        blockIdx.x, blockIdx.y, As, Bs);
}

// ---------------------------------------------------------------------------
// Per-head V transpose
// ---------------------------------------------------------------------------
__global__ __launch_bounds__(256)
void vhead_transpose(const __bf16* __restrict__ v, __bf16* __restrict__ vt)
{
    __shared__ __bf16 tile[32][33];
    int tx = threadIdx.x & 31, ty = threadIdx.x >> 5;
    int s0 = blockIdx.x * 32;
    int d0 = blockIdx.y * 32;
    int h = blockIdx.z;
    for (int i = 0; i < 4; i++)
        tile[ty + i * 8][tx] = v[(size_t)(s0 + ty + i * 8) * 3072 + h * DK + d0 + tx];
    __syncthreads();
    for (int i = 0; i < 4; i++)
        vt[(size_t)(h * DK + d0 + ty + i * 8) * S_LEN + s0 + tx] = tile[tx][ty + i * 8];
}

// ---------------------------------------------------------------------------
// LayerNorm (standalone, for LN2)
// ---------------------------------------------------------------------------
__global__ __launch_bounds__(256)
void ln_kernel(const float* __restrict__ x, const float* __restrict__ gamma,
               const float* __restrict__ beta, __bf16* __restrict__ outb,
               float* __restrict__ outf)
{
    __shared__ float red[8];
    ln_row(blockIdx.x, x, gamma, beta, outb, outf, red);
}

// ---------------------------------------------------------------------------
// attn_flash v5 + P upper-triangle zero-fill backfill (unchanged from r10)
// ---------------------------------------------------------------------------
__global__ __launch_bounds__(256, 3)
void attn_flash(const __bf16* __restrict__ qkv, const __bf16* __restrict__ vt,
                float* __restrict__ Obuf, __bf16* __restrict__ ctx,
                float* __restrict__ P)
{
    __shared__ char Ks[16384];
    __shared__ char Vs[16384];
    __shared__ char Plds[4][4096];
    const int tid = threadIdx.x;

    if (blockIdx.x >= 512) {
        int id = blockIdx.x - 512;          // [0,1920)
        int h = id / 120;
        int pr = id - h * 120;
        int qt = 0, acc = 0;
        while (pr >= acc + 15 - qt) { acc += 15 - qt; qt++; }
        int kt = qt + 1 + (pr - acc);
        f32x4 z = {0.f, 0.f, 0.f, 0.f};
        float* base = P + (size_t)h * S_LEN * S_LEN + (size_t)(qt * 128) * S_LEN + kt * 128;
        #pragma unroll
        for (int i = 0; i < 16; i++) {
            int idx = i * 256 + tid;
            int row = idx >> 5, c = idx & 31;
            __builtin_nontemporal_store(z, (f32x4*)(base + (size_t)row * S_LEN + c * 4));
        }
        return;
    }

    const int lane = tid & 63;
    const int w = tid >> 6;
    const int lrow = lane & 15;
    const int g = lane >> 4;
    const int h = blockIdx.x & 15;
    const int b = 31 - ((int)blockIdx.x >> 4);
    const int qg = b * 64 + w * 16 + lrow;
    const int ntiles = (b >> 1) + 1;
    const float c1 = 0.18033688f;
    const __bf16* ksec = qkv + 1024;
    char* plB = Plds[w];

    bf16x8 qf[2];
    qf[0] = *(const bf16x8*)(qkv + (size_t)qg * 3072 + h * DK + g * 8);
    qf[1] = *(const bf16x8*)(qkv + (size_t)qg * 3072 + h * DK + 32 + g * 8);

    float m2 = -1e30f, l = 0.f;
    f32x4 acc2[4];
    #pragma unroll
    for (int i = 0; i < 4; i++) acc2[i] = (f32x4){0.f, 0.f, 0.f, 0.f};

    const int sKrow = (w << 3) + (lane >> 3);
    const int sKch = lane & 7;
    const int sVrow = (w << 2) + (lane >> 4);
    const int sVch = lane & 15;
    char* const KsW = Ks + w * 1024;
    char* const VsW = Vs + w * 1024;

    for (int kt = 0; kt < ntiles; kt++) {
        #pragma unroll
        for (int p = 0; p < 4; p++) {
            int row = sKrow + p * 32;
            int ch = sKch ^ (row & 7);
            gload16(ksec + (size_t)(kt * 128 + row) * 3072 + h * DK + ch * 8,
                    KsW + p * 4096 + lane * 16);
        }
        #pragma unroll
        for (int p = 0; p < 4; p++) {
            int row = sVrow + p * 16;
            int ch = sVch ^ (row & 7);
            gload16(vt + (size_t)(h * DK + row) * S_LEN + kt * 128 + ch * 8,
                    VsW + p * 4096 + lane * 16);
        }
        asm volatile("s_waitcnt vmcnt(0)" ::: "memory");
        __syncthreads();

        f32x4 acc[8];
        #pragma unroll
        for (int mf = 0; mf < 8; mf++) acc[mf] = (f32x4){0.f, 0.f, 0.f, 0.f};
        #pragma unroll
        for (int kk = 0; kk < 2; kk++)
            #pragma unroll
            for (int mf = 0; mf < 8; mf++) {
                int row = mf * 16 + lrow;
                bf16x8 kf = *(const bf16x8*)(Ks + row * 128 + (((kk * 4 + g) ^ (row & 7)) << 4));
                acc[mf] = MFMA16(kf, qf[kk], acc[mf]);
            }

        float s[8][4];
        float tmx = -1e30f;
        const bool lastT = (kt == ntiles - 1);
        #pragma unroll
        for (int mf = 0; mf < 8; mf++) {
            int kvb = kt * 128 + mf * 16 + g * 4;
            #pragma unroll
            for (int r = 0; r < 4; r++) {
                float sv = acc[mf][r] * c1;
                if (lastT) sv = (kvb + r <= qg) ? sv : -1e30f;
                s[mf][r] = sv;
                tmx = fmaxf(tmx, sv);
            }
        }
        if (!__all((int)(tmx <= m2 + 6.f))) {
            float tm = fmaxf(tmx, __shfl_xor(tmx, 16));
            tm = fmaxf(tm, __shfl_xor(tm, 32));
            float nm = fmaxf(m2, tm);
            float sc = exp2f(m2 - nm);
            l *= sc;
            #pragma unroll
            for (int md = 0; md < 4; md++) acc2[md] *= sc;
            m2 = nm;
        }
        float sum = 0.f;
        #pragma unroll
        for (int mf = 0; mf < 8; mf++) {
            float p0 = exp2f(s[mf][0] - m2);
            float p1 = exp2f(s[mf][1] - m2);
            float p2 = exp2f(s[mf][2] - m2);
            float p3 = exp2f(s[mf][3] - m2);
            sum += (p0 + p1) + (p2 + p3);
            uint2 pk;
            pk.x = pack_bf16x2(p0, p1);
            pk.y = pack_bf16x2(p2, p3);
            *(uint2*)(plB + ((lrow * 256 + mf * 32 + g * 8) ^ ((lrow & 7) << 4))) = pk;
        }
        l += sum;

        #pragma unroll
        for (int ks = 0; ks < 4; ks++) {
            bf16x8 pf = *(bf16x8*)(plB + ((lrow * 256 + ks * 64 + g * 16) ^ ((lrow & 7) << 4)));
            #pragma unroll
            for (int md = 0; md < 4; md++) {
                int row = md * 16 + lrow;
                bf16x8 vf = *(const bf16x8*)(Vs + row * 256 + (((ks * 4 + g) ^ (row & 7)) << 4));
                acc2[md] = MFMA16(vf, pf, acc2[md]);
            }
        }
        __syncthreads();
    }

    l += __shfl_xor(l, 16);
    l += __shfl_xor(l, 32);
    float li = 1.f / l;
    if (lane < 16)
        Obuf[h * S_LEN + qg] = -m2 - log2f(l);
    #pragma unroll
    for (int md = 0; md < 4; md++) {
        uint2 pk;
        pk.x = pack_bf16x2(acc2[md][0] * li, acc2[md][1] * li);
        pk.y = pack_bf16x2(acc2[md][2] * li, acc2[md][3] * li);
        *(uint2*)(ctx + (size_t)qg * D_MOD + h * DK + md * 16 + g * 4) = pk;
    }
}

// ---------------------------------------------------------------------------
// ff1_pwrite: [0,512) ff1 GEMM; [512,1600) P tiles for heads [0,8)
// ---------------------------------------------------------------------------
__global__ __launch_bounds__(256)
void ff1_pwrite(const __bf16* __restrict__ A, const __bf16* __restrict__ BT,
                const float* __restrict__ bias, __bf16* __restrict__ Cb,
                const __bf16* __restrict__ qkv, const float* __restrict__ Obuf,
                float* __restrict__ P)
{
    __shared__ uint4 As[128 * 8];
    __shared__ uint4 Bs[128 * 8];
    if (blockIdx.x < 512) {
        int bid = blockIdx.x;
        gemm_dev<128, true, false, false, false, true>(
            A, BT, bias, nullptr, nullptr, nullptr, Cb,
            D_FF, 1024, 1024, bid & 31, bid >> 5, As, Bs);
        return;
    }
    int idp = blockIdx.x - 512;      // [0,1088)
    int h = idp / 136;
    int tt = idp - h * 136;
    int qt = 0;
    while (tt > qt) { tt -= qt + 1; qt++; }
    pwrite_tile(qkv, Obuf, P, h, qt, tt);
}

// ---------------------------------------------------------------------------
// ff2_pwrite: [0,512) ff2 split-K halves -> partA/partB (f32);
// [512,1600) P tiles for heads [8,16)
// ---------------------------------------------------------------------------
__global__ __launch_bounds__(256)
void ff2_pwrite(const __bf16* __restrict__ ff1_b, const __bf16* __restrict__ Wf2T,
                float* __restrict__ partA, float* __restrict__ partB,
                const __bf16* __restrict__ qkv, const float* __restrict__ Obuf,
                float* __restrict__ P)
{
    __shared__ uint4 As[128 * 8];
    __shared__ uint4 Bs[64 * 8];
    if (blockIdx.x < 512) {
        int half = blockIdx.x >> 8;
        int b2 = blockIdx.x & 255;
        const __bf16* Ah = ff1_b + half * 2048;
        const __bf16* Bh = Wf2T + half * 2048;
        float* Cf = half ? partB : partA;
        gemm_dev<64, false, false, false, true, false>(
            Ah, Bh, nullptr, nullptr, nullptr, Cf, nullptr,
            1024, 4096, 2048, b2 & 15, b2 >> 4, As, Bs);
        return;
    }
    int idp = blockIdx.x - 512;      // [0,1088)
    int h = 8 + idp / 136;
    int tt = idp - (idp / 136) * 136;
    int qt = 0;
    while (tt > qt) { tt -= qt + 1; qt++; }
    pwrite_tile(qkv, Obuf, P, h, qt, tt);
}

// ---------------------------------------------------------------------------
// ff2_reduce: out = partA + partB + norm2 + bf2
// ---------------------------------------------------------------------------
__global__ __launch_bounds__(256)
void ff2_reduce(const float* __restrict__ partA, const float* __restrict__ partB,
                const float* __restrict__ norm2f, const float* __restrict__ bf2,
                float* __restrict__ outp)
{
    int idx = blockIdx.x * 256 + threadIdx.x;
    int col = (idx * 4) & 1023;
    f32x4 a = *(const f32x4*)(partA + (size_t)idx * 4);
    f32x4 b = *(const f32x4*)(partB + (size_t)idx * 4);
    f32x4 n = *(const f32x4*)(norm2f + (size_t)idx * 4);
    f32x4 bb = *(const f32x4*)(bf2 + col);
    f32x4 o = a + b + n + bb;
    *(f32x4*)(outp + (size_t)idx * 4) = o;
}

// ---------------------------------------------------------------------------
extern "C" void kernel_launch(void* const* d_in, const int* in_sizes, int n_in,
                              void* d_out, int out_size, void* d_ws, size_t ws_size,
                              hipStream_t stream)
{
    const float* x     = (const float*)d_in[0];
    const float* g1    = (const float*)d_in[1];
    const float* beta1 = (const float*)d_in[2];
    const float* W_in  = (const float*)d_in[3];
    const float* b_in  = (const float*)d_in[4];
    const float* Wq    = (const float*)d_in[5];
    const float* bq    = (const float*)d_in[6];
    const float* Wk    = (const float*)d_in[7];
    const float* bk    = (const float*)d_in[8];
    const float* Wv    = (const float*)d_in[9];
    const float* bv    = (const float*)d_in[10];
    const float* Wo    = (const float*)d_in[11];
    const float* bo    = (const float*)d_in[12];
    const float* W2    = (const float*)d_in[13];
    const float* b2    = (const float*)d_in[14];
    const float* g2    = (const float*)d_in[15];
    const float* beta2 = (const float*)d_in[16];
    const float* Wf1   = (const float*)d_in[17];
    const float* bf1   = (const float*)d_in[18];
    const float* Wf2   = (const float*)d_in[19];
    const float* bf2   = (const float*)d_in[20];

    float* outp = (float*)d_out;                    // [2048][1024]
    float* Pout = outp + (size_t)S_LEN * D_MOD;     // [16][2048][2048]

    char* p = (char*)d_ws;
    auto alloc = [&](size_t b) -> void* {
        void* r = (void*)p;
        p += (b + 255) & ~(size_t)255;
        return r;
    };
    __bf16* WqkvT    = (__bf16*)alloc((size_t)3072 * 1024 * 2);
    __bf16* W2T      = (__bf16*)alloc((size_t)1024 * 1024 * 2);
    __bf16* Wf1T     = (__bf16*)alloc((size_t)D_FF * D_MOD * 2);
    __bf16* Wf2T     = (__bf16*)alloc((size_t)D_MOD * D_FF * 2);
    __bf16* WqkvCT   = (__bf16*)alloc((size_t)3072 * 1024 * 2);
    __bf16* WcombT   = (__bf16*)alloc((size_t)1024 * 1024 * 2);
    float*  bqkv     = (float*)alloc((size_t)3072 * 4);
    float*  bcomb    = (float*)alloc((size_t)1024 * 4);
    float*  biaspart = (float*)alloc((size_t)8 * 4096 * 4);
    __bf16* xn_b     = (__bf16*)alloc((size_t)S_LEN * D_MOD * 2);
    __bf16* qkv_b    = (__bf16*)alloc((size_t)S_LEN * 3072 * 2);
    __bf16* VT       = (__bf16*)alloc((size_t)N_HEADS * DK * S_LEN * 2);
    __bf16* ctx_b    = (__bf16*)alloc((size_t)S_LEN * D_MOD * 2);
    float*  part1f   = (float*)alloc((size_t)S_LEN * D_MOD * 4);
    float*  norm2f   = (float*)alloc((size_t)S_LEN * D_MOD * 4);
    __bf16* norm2b   = (__bf16*)alloc((size_t)S_LEN * D_MOD * 2);
    __bf16* ff1_b    = (__bf16*)alloc((size_t)S_LEN * D_FF * 2);
    float*  Obuf     = (float*)alloc((size_t)N_HEADS * S_LEN * 4);
    float*  ffpartB  = (float*)alloc((size_t)S_LEN * D_MOD * 4);
    // aliases (lifetimes disjoint, stream-ordered):
    __bf16* Win_b   = (__bf16*)part1f;   // weight staging before part1 GEMM
    __bf16* Wo_b    = (__bf16*)norm2f;   // weight staging before ln2
    float*  ffpartA = part1f;            // split-K partial after ln2 consumed part1f

    dim3 blk(256);

    prep1<<<dim3(14464), blk, 0, stream>>>(Wq, Wk, Wv, W2, Wf1, Wf2, W_in, Wo,
                                           b_in, bo, WqkvT, W2T, Wf1T, Wf2T,
                                           Win_b, Wo_b, biaspart);

    prep2<<<dim3(2576), blk, 0, stream>>>(WqkvT, Win_b, WqkvCT, W2T, Wo_b, WcombT,
                                          biaspart, bq, bk, bv, b2, bqkv, bcomb,
                                          x, g1, beta1, xn_b);

    gemm_kernel<128, false, false, false, false, true><<<dim3(24, 16), blk, 0, stream>>>(
        xn_b, WqkvCT, bqkv, nullptr, nullptr, nullptr, qkv_b, 3072, 1024, 1024);

    vhead_transpose<<<dim3(64, 2, 16), blk, 0, stream>>>(qkv_b + 2048, VT);

    attn_flash<<<dim3(512 + 1920), blk, 0, stream>>>(qkv_b, VT, Obuf, ctx_b, Pout);

    gemm_kernel<64, false, true, false, true, false><<<dim3(16, 16), blk, 0, stream>>>(
        ctx_b, WcombT, bcomb, x, nullptr, part1f, nullptr, 1024, 1024, 1024);

    ln_kernel<<<S_LEN, blk, 0, stream>>>(part1f, g2, beta2, norm2b, norm2f);

    ff1_pwrite<<<dim3(512 + 1088), blk, 0, stream>>>(
        norm2b, Wf1T, bf1, ff1_b, qkv_b, Obuf, Pout);

    ff2_pwrite<<<dim3(512 + 1088), blk, 0, stream>>>(
        ff1_b, Wf2T, ffpartA, ffpartB, qkv_b, Obuf, Pout);

    ff2_reduce<<<dim3(2048), blk, 0, stream>>>(ffpartA, ffpartB, norm2f, bf2, outp);
}

// Round 12
// 260.186 us; speedup vs baseline: 1.6529x; 1.0061x over previous
//
#include <hip/hip_runtime.h>
#include <hip/hip_bf16.h>
#include <cstdint>

#define S_LEN 2048
#define D_MOD 1024
#define N_HEADS 16
#define DK 64
#define D_FF 4096

typedef __bf16 bf16x8 __attribute__((ext_vector_type(8)));
typedef float f32x4 __attribute__((ext_vector_type(4)));

#define MFMA16(a, b, c) __builtin_amdgcn_mfma_f32_16x16x32_bf16((a), (b), (c), 0, 0, 0)

__device__ inline unsigned pack_bf16x2(float a, float b)
{
    unsigned short ua = __builtin_bit_cast(unsigned short, (__bf16)a);
    unsigned short ub = __builtin_bit_cast(unsigned short, (__bf16)b);
    return (unsigned)ua | ((unsigned)ub << 16);
}

// async global->LDS, 16B per lane; LDS dest must equal waveBase + lane*16
__device__ inline void gload16(const void* g, void* l)
{
    __builtin_amdgcn_global_load_lds(
        (const __attribute__((address_space(1))) unsigned int*)g,
        (__attribute__((address_space(3))) unsigned int*)l, 16, 0, 0);
}

// ---------------------------------------------------------------------------
// Shared GEMM block body. WVT: also write transposed VT for cols >= 2048
// (qkv fusion: v section -> VT[h*64+d][s]).
// ---------------------------------------------------------------------------
template<int BN, bool RELU, bool RES, bool RES2, bool WF32, bool WBF16, bool WVT>
__device__ __forceinline__
void gemm_dev(const __bf16* __restrict__ A, const __bf16* __restrict__ BT,
              const float* __restrict__ bias, const float* __restrict__ res,
              const float* __restrict__ res2,
              float* __restrict__ Cf, __bf16* __restrict__ Cb,
              __bf16* __restrict__ vt,
              int N, int Kst, int Klp, int bx, int by,
              uint4* As, uint4* Bs)
{
    constexpr int NFRAG = BN / 32;
    const int tid = threadIdx.x;
    const int lane = tid & 63;
    const int w = tid >> 6;
    const int lrow = lane & 15;
    const int g = lane >> 4;
    const int bm = by * 128;
    const int bn = bx * BN;
    const int wrow = (w >> 1) * 64;
    const int wcol = (w & 1) * (BN / 2);

    f32x4 acc[4][NFRAG];
    for (int m = 0; m < 4; m++)
        for (int n = 0; n < NFRAG; n++)
            acc[m][n] = (f32x4){0.f, 0.f, 0.f, 0.f};

    const int srow = tid >> 3;
    const int sc = tid & 7;
    const __bf16* Ag = A + (size_t)(bm + srow) * Kst + sc * 8;
    const __bf16* Bg = BT + (size_t)(bn + srow) * Kst + sc * 8;

    for (int kt = 0; kt < Klp; kt += 64) {
        __syncthreads();
        #pragma unroll
        for (int p = 0; p < 4; p++)
            gload16(Ag + (size_t)(p * 32) * Kst + kt, &As[(srow + p * 32) * 8 + sc]);
        #pragma unroll
        for (int p = 0; p < NFRAG; p++)
            gload16(Bg + (size_t)(p * 32) * Kst + kt, &Bs[(srow + p * 32) * 8 + sc]);
        asm volatile("s_waitcnt vmcnt(0)" ::: "memory");
        __syncthreads();
        #pragma unroll
        for (int kk = 0; kk < 2; kk++) {
            bf16x8 af[4], bfr[NFRAG];
            int c = kk * 4 + g;
            #pragma unroll
            for (int m = 0; m < 4; m++)
                af[m] = __builtin_bit_cast(bf16x8, As[(wrow + m * 16 + lrow) * 8 + c]);
            #pragma unroll
            for (int n = 0; n < NFRAG; n++)
                bfr[n] = __builtin_bit_cast(bf16x8, Bs[(wcol + n * 16 + lrow) * 8 + c]);
            #pragma unroll
            for (int m = 0; m < 4; m++)
                #pragma unroll
                for (int n = 0; n < NFRAG; n++)
                    acc[m][n] = MFMA16(af[m], bfr[n], acc[m][n]);
        }
    }

    for (int n = 0; n < NFRAG; n++) {
        int col = bn + wcol + n * 16 + lrow;
        float bval = bias ? bias[col] : 0.f;
        for (int m = 0; m < 4; m++) {
            int row0 = bm + wrow + m * 16 + g * 4;
            float vv[4];
            for (int r = 0; r < 4; r++) {
                int row = row0 + r;
                float v = acc[m][n][r] + bval;
                if (RELU) v = fmaxf(v, 0.f);
                if (RES) v += res[(size_t)row * N + col];
                if (RES2) v += res2[(size_t)row * N + col];
                vv[r] = v;
                if (WF32) Cf[(size_t)row * N + col] = v;
                if (WBF16) Cb[(size_t)row * N + col] = (__bf16)v;
            }
            if (WVT && col >= 2048) {
                uint2 pk;
                pk.x = pack_bf16x2(vv[0], vv[1]);
                pk.y = pack_bf16x2(vv[2], vv[3]);
                *(uint2*)(vt + (size_t)(col - 2048) * S_LEN + row0) = pk;
            }
        }
    }
}

// ---------------------------------------------------------------------------
// LayerNorm row body
// ---------------------------------------------------------------------------
__device__ __forceinline__
void ln_row(int row, const float* __restrict__ x, const float* __restrict__ gamma,
            const float* __restrict__ beta, __bf16* __restrict__ outb,
            float* __restrict__ outf, float* red)
{
    int tid = threadIdx.x;
    const float4 v = ((const float4*)(x + (size_t)row * D_MOD))[tid];
    float s = v.x + v.y + v.z + v.w;
    float sq = v.x * v.x + v.y * v.y + v.z * v.z + v.w * v.w;
    for (int off = 32; off; off >>= 1) {
        s += __shfl_down(s, off);
        sq += __shfl_down(sq, off);
    }
    int wid = tid >> 6;
    if ((tid & 63) == 0) { red[wid] = s; red[wid + 4] = sq; }
    __syncthreads();
    s = red[0] + red[1] + red[2] + red[3];
    sq = red[4] + red[5] + red[6] + red[7];
    float mean = s * (1.f / D_MOD);
    float var = fmaxf(sq * (1.f / D_MOD) - mean * mean, 0.f);
    float inv = 1.f / (sqrtf(var) + 1e-6f);
    float4 gv = ((const float4*)gamma)[tid];
    float4 bv = ((const float4*)beta)[tid];
    float y0 = gv.x * ((v.x - mean) * inv) + bv.x;
    float y1 = gv.y * ((v.y - mean) * inv) + bv.y;
    float y2 = gv.z * ((v.z - mean) * inv) + bv.z;
    float y3 = gv.w * ((v.w - mean) * inv) + bv.w;
    uint2 pk;
    pk.x = pack_bf16x2(y0, y1);
    pk.y = pack_bf16x2(y2, y3);
    ((uint2*)(outb + (size_t)row * D_MOD))[tid] = pk;
    if (outf) {
        float4 o = {y0, y1, y2, y3};
        ((float4*)(outf + (size_t)row * D_MOD))[tid] = o;
    }
}

// ---------------------------------------------------------------------------
// P tile write body (kt <= qt)
// ---------------------------------------------------------------------------
__device__ __forceinline__
void pwrite_tile(const __bf16* __restrict__ qkv, const float* __restrict__ Obuf,
                 float* __restrict__ P, int h, int qt, int kt)
{
    const int tid = threadIdx.x;
    const int lane = tid & 63;
    const int w = tid >> 6;
    const int lrow = lane & 15;
    const int g = lane >> 4;
    const float c1 = 0.18033688f;
    const __bf16* ksec = qkv + 1024;
    const size_t Pb = (size_t)h * S_LEN * S_LEN;

    bf16x8 qfr[2][2];
    #pragma unroll
    for (int qq = 0; qq < 2; qq++)
        #pragma unroll
        for (int kk = 0; kk < 2; kk++)
            qfr[qq][kk] = *(const bf16x8*)(qkv +
                (size_t)(qt * 128 + w * 32 + qq * 16 + lrow) * 3072 + h * DK + kk * 32 + g * 8);

    f32x4 acc[2][8];
    #pragma unroll
    for (int qq = 0; qq < 2; qq++)
        #pragma unroll
        for (int mf = 0; mf < 8; mf++) acc[qq][mf] = (f32x4){0.f, 0.f, 0.f, 0.f};
    #pragma unroll
    for (int kk = 0; kk < 2; kk++) {
        #pragma unroll
        for (int mf = 0; mf < 8; mf++) {
            bf16x8 kf = *(const bf16x8*)(ksec +
                (size_t)(kt * 128 + mf * 16 + lrow) * 3072 + h * DK + kk * 32 + g * 8);
            acc[0][mf] = MFMA16(kf, qfr[0][kk], acc[0][mf]);
            acc[1][mf] = MFMA16(kf, qfr[1][kk], acc[1][mf]);
        }
    }

    #pragma unroll
    for (int qq = 0; qq < 2; qq++) {
        int q = qt * 128 + w * 32 + qq * 16 + lrow;
        float offv = Obuf[h * S_LEN + q];
        float* prow = P + Pb + (size_t)q * S_LEN;
        if (kt == qt) {
            #pragma unroll
            for (int mf = 0; mf < 8; mf++) {
                int kvb = kt * 128 + mf * 16 + g * 4;
                f32x4 st;
                st[0] = (kvb + 0 <= q) ? exp2f(acc[qq][mf][0] * c1 + offv) : 0.f;
                st[1] = (kvb + 1 <= q) ? exp2f(acc[qq][mf][1] * c1 + offv) : 0.f;
                st[2] = (kvb + 2 <= q) ? exp2f(acc[qq][mf][2] * c1 + offv) : 0.f;
                st[3] = (kvb + 3 <= q) ? exp2f(acc[qq][mf][3] * c1 + offv) : 0.f;
                __builtin_nontemporal_store(st, (f32x4*)(prow + kvb));
            }
        } else {
            #pragma unroll
            for (int mf = 0; mf < 8; mf++) {
                int kvb = kt * 128 + mf * 16 + g * 4;
                f32x4 st;
                st[0] = exp2f(acc[qq][mf][0] * c1 + offv);
                st[1] = exp2f(acc[qq][mf][1] * c1 + offv);
                st[2] = exp2f(acc[qq][mf][2] * c1 + offv);
                st[3] = exp2f(acc[qq][mf][3] * c1 + offv);
                __builtin_nontemporal_store(st, (f32x4*)(prow + kvb));
            }
        }
    }
}

// zero-fill one strict-upper-triangle 128x128 P tile, zid in [0,1920)
__device__ __forceinline__
void zfill_tile(float* __restrict__ P, int zid)
{
    int tid = threadIdx.x;
    int h = zid / 120;
    int pr = zid - h * 120;
    int qt = 0, acc = 0;
    while (pr >= acc + 15 - qt) { acc += 15 - qt; qt++; }
    int kt = qt + 1 + (pr - acc);
    f32x4 z = {0.f, 0.f, 0.f, 0.f};
    float* base = P + (size_t)h * S_LEN * S_LEN + (size_t)(qt * 128) * S_LEN + kt * 128;
    #pragma unroll
    for (int i = 0; i < 16; i++) {
        int idx = i * 256 + tid;
        int row = idx >> 5, c = idx & 31;
        __builtin_nontemporal_store(z, (f32x4*)(base + (size_t)row * S_LEN + c * 4));
    }
}

// ---------------------------------------------------------------------------
// prep1: [0,12288) weight transposes; [12288,14336) converts; [14336,14464)
// bias_stage1 partials.
// ---------------------------------------------------------------------------
__global__ __launch_bounds__(256)
void prep1(const float* __restrict__ Wq, const float* __restrict__ Wk,
           const float* __restrict__ Wv, const float* __restrict__ W2,
           const float* __restrict__ Wf1, const float* __restrict__ Wf2,
           const float* __restrict__ W_in, const float* __restrict__ Wo,
           const float* __restrict__ b_in, const float* __restrict__ bo,
           __bf16* __restrict__ WqkvT, __bf16* __restrict__ W2T,
           __bf16* __restrict__ Wf1T, __bf16* __restrict__ Wf2T,
           __bf16* __restrict__ Win_b, __bf16* __restrict__ Wo_b,
           float* __restrict__ part)
{
    __shared__ float tile[32][33];
    int id = blockIdx.x;
    int tid = threadIdx.x;
    if (id < 12288) {
        const float* W; __bf16* WT; int K, N, n0, k0;
        if (id < 4096) {
            int m = id >> 10; id &= 1023;
            K = 1024; N = 1024;
            n0 = (id & 31) * 32; k0 = (id >> 5) * 32;
            W = m == 0 ? Wq : (m == 1 ? Wk : (m == 2 ? Wv : W2));
            WT = m == 3 ? W2T : WqkvT + (size_t)m * 1024 * 1024;
        } else if (id < 8192) {
            id -= 4096;
            K = 1024; N = 4096;
            n0 = (id & 127) * 32; k0 = (id >> 7) * 32;
            W = Wf1; WT = Wf1T;
        } else {
            id -= 8192;
            K = 4096; N = 1024;
            n0 = (id & 31) * 32; k0 = (id >> 5) * 32;
            W = Wf2; WT = Wf2T;
        }
        int tx = tid & 31, ty = tid >> 5;
        for (int i = 0; i < 4; i++)
            tile[ty + i * 8][tx] = W[(size_t)(k0 + ty + i * 8) * N + n0 + tx];
        __syncthreads();
        for (int i = 0; i < 4; i++)
            WT[(size_t)(n0 + ty + i * 8) * K + k0 + tx] = (__bf16)tile[tx][ty + i * 8];
        return;
    }
    id -= 12288;
    if (id < 2048) {
        const float* W = id < 1024 ? W_in : Wo;
        __bf16* o = id < 1024 ? Win_b : Wo_b;
        int i = (id & 1023) * 256 + tid;
        float4 v = ((const float4*)W)[i];
        uint2 pk;
        pk.x = pack_bf16x2(v.x, v.y);
        pk.y = pack_bf16x2(v.z, v.w);
        ((uint2*)o)[i] = pk;
        return;
    }
    id -= 2048;
    {
        int n = (id & 15) * 256 + tid;
        int kc = id >> 4;
        int sel = n >> 10, col = n & 1023;
        const float* W = sel == 0 ? Wq : (sel == 1 ? Wk : (sel == 2 ? Wv : W2));
        const float* src = sel < 3 ? b_in : bo;
        float s = 0.f;
        for (int k = kc * 128; k < kc * 128 + 128; k++)
            s += src[k] * W[(size_t)k * 1024 + col];
        part[kc * 4096 + n] = s;
    }
}

// ---------------------------------------------------------------------------
// prep2: [0,384) WqkvCT gemm; [384,512) WcombT gemm; [512,528) bias_stage2;
// [528,2576) LN1 rows.
// ---------------------------------------------------------------------------
__global__ __launch_bounds__(256, 2)
void prep2(const __bf16* __restrict__ WqkvT, const __bf16* __restrict__ Win_b,
           __bf16* __restrict__ WqkvCT,
           const __bf16* __restrict__ W2T, const __bf16* __restrict__ Wo_b,
           __bf16* __restrict__ WcombT,
           const float* __restrict__ part,
           const float* __restrict__ bq, const float* __restrict__ bk,
           const float* __restrict__ bv, const float* __restrict__ b2,
           float* __restrict__ bqkv, float* __restrict__ bcomb,
           const float* __restrict__ x, const float* __restrict__ g1,
           const float* __restrict__ beta1, __bf16* __restrict__ xn_b)
{
    __shared__ uint4 As[128 * 8];
    __shared__ uint4 Bs[64 * 8];
    int id = blockIdx.x;
    int tid = threadIdx.x;
    if (id < 384) {
        gemm_dev<64, false, false, false, false, true, false>(
            WqkvT, Win_b, nullptr, nullptr, nullptr, nullptr, WqkvCT, nullptr,
            1024, 1024, 1024, id & 15, id >> 4, As, Bs);
        return;
    }
    id -= 384;
    if (id < 128) {
        gemm_dev<64, false, false, false, false, true, false>(
            W2T, Wo_b, nullptr, nullptr, nullptr, nullptr, WcombT, nullptr,
            1024, 1024, 1024, id & 15, id >> 4, As, Bs);
        return;
    }
    id -= 128;
    if (id < 16) {
        int n = id * 256 + tid;
        int sel = n >> 10, col = n & 1023;
        float s = sel == 0 ? bq[col] : (sel == 1 ? bk[col] : (sel == 2 ? bv[col] : b2[col]));
        for (int kc = 0; kc < 8; kc++) s += part[kc * 4096 + n];
        if (n < 3072) bqkv[n] = s; else bcomb[col] = s;
        return;
    }
    id -= 16;
    ln_row(id, x, g1, beta1, xn_b, nullptr, (float*)As);
}

// ---------------------------------------------------------------------------
// qkv_zf: [0,384) qkv GEMM (with fused VT epilogue); [384,1344) P zero-fill
// ---------------------------------------------------------------------------
__global__ __launch_bounds__(256, 2)
void qkv_zf(const __bf16* __restrict__ xn_b, const __bf16* __restrict__ WqkvCT,
            const float* __restrict__ bqkv, __bf16* __restrict__ qkv_b,
            __bf16* __restrict__ vt, float* __restrict__ P)
{
    __shared__ uint4 As[128 * 8];
    __shared__ uint4 Bs[128 * 8];
    if (blockIdx.x < 384) {
        int bid = blockIdx.x;
        gemm_dev<128, false, false, false, false, true, true>(
            xn_b, WqkvCT, bqkv, nullptr, nullptr, nullptr, qkv_b, vt,
            3072, 1024, 1024, bid % 24, bid / 24, As, Bs);
        return;
    }
    zfill_tile(P, blockIdx.x - 384);
}

// ---------------------------------------------------------------------------
// Standalone GEMM kernel (part1)
// ---------------------------------------------------------------------------
template<int BN, bool RELU, bool RES, bool RES2, bool WF32, bool WBF16>
__global__ __launch_bounds__(256, 2)
void gemm_kernel(const __bf16* __restrict__ A, const __bf16* __restrict__ BT,
                 const float* __restrict__ bias, const float* __restrict__ res,
                 const float* __restrict__ res2,
                 float* __restrict__ Cf, __bf16* __restrict__ Cb,
                 int N, int Kst, int Klp)
{
    __shared__ uint4 As[128 * 8];
    __shared__ uint4 Bs[BN * 8];
    gemm_dev<BN, RELU, RES, RES2, WF32, WBF16, false>(
        A, BT, bias, res, res2, Cf, Cb, nullptr, N, Kst, Klp,
        blockIdx.x, blockIdx.y, As, Bs);
}

// ---------------------------------------------------------------------------
// LayerNorm (standalone, for LN2)
// ---------------------------------------------------------------------------
__global__ __launch_bounds__(256)
void ln_kernel(const float* __restrict__ x, const float* __restrict__ gamma,
               const float* __restrict__ beta, __bf16* __restrict__ outb,
               float* __restrict__ outf)
{
    __shared__ float red[8];
    ln_row(blockIdx.x, x, gamma, beta, outb, outf, red);
}

// ---------------------------------------------------------------------------
// attn_flash v6: double-buffered K/V LDS with counted-vmcnt prefetch.
// Flash blocks [0,512); blocks [512,1472): P zero-fill (zid 960..1919).
// ---------------------------------------------------------------------------
__global__ __launch_bounds__(256, 2)
void attn_flash(const __bf16* __restrict__ qkv, const __bf16* __restrict__ vt,
                float* __restrict__ Obuf, __bf16* __restrict__ ctx,
                float* __restrict__ P)
{
    __shared__ char Ks[2][16384];
    __shared__ char Vs[2][16384];
    __shared__ char Plds[4][4096];
    const int tid = threadIdx.x;

    if (blockIdx.x >= 512) {
        zfill_tile(P, 960 + (int)blockIdx.x - 512);
        return;
    }

    const int lane = tid & 63;
    const int w = tid >> 6;
    const int lrow = lane & 15;
    const int g = lane >> 4;
    const int h = blockIdx.x & 15;
    const int b = 31 - ((int)blockIdx.x >> 4);
    const int qg = b * 64 + w * 16 + lrow;
    const int ntiles = (b >> 1) + 1;
    const float c1 = 0.18033688f;
    const __bf16* ksec = qkv + 1024;
    char* plB = Plds[w];

    bf16x8 qf[2];
    qf[0] = *(const bf16x8*)(qkv + (size_t)qg * 3072 + h * DK + g * 8);
    qf[1] = *(const bf16x8*)(qkv + (size_t)qg * 3072 + h * DK + 32 + g * 8);

    float m2 = -1e30f, l = 0.f;
    f32x4 acc2[4];
    #pragma unroll
    for (int i = 0; i < 4; i++) acc2[i] = (f32x4){0.f, 0.f, 0.f, 0.f};

    const int sKrow = (w << 3) + (lane >> 3);
    const int sKch = lane & 7;
    const int sVrow = (w << 2) + (lane >> 4);
    const int sVch = lane & 15;

    auto stage = [&](int kt, int tb) {
        char* KsW = Ks[tb] + w * 1024;
        char* VsW = Vs[tb] + w * 1024;
        #pragma unroll
        for (int p = 0; p < 4; p++) {
            int row = sKrow + p * 32;
            int ch = sKch ^ (row & 7);
            gload16(ksec + (size_t)(kt * 128 + row) * 3072 + h * DK + ch * 8,
                    KsW + p * 4096 + lane * 16);
        }
        #pragma unroll
        for (int p = 0; p < 4; p++) {
            int row = sVrow + p * 16;
            int ch = sVch ^ (row & 7);
            gload16(vt + (size_t)(h * DK + row) * S_LEN + kt * 128 + ch * 8,
                    VsW + p * 4096 + lane * 16);
        }
    };

    stage(0, 0);

    for (int kt = 0; kt < ntiles; kt++) {
        const int cur = kt & 1;
        if (kt + 1 < ntiles) {
            stage(kt + 1, cur ^ 1);
            asm volatile("s_waitcnt vmcnt(8)" ::: "memory");   // tile kt's loads done
        } else {
            asm volatile("s_waitcnt vmcnt(0)" ::: "memory");
        }
        __syncthreads();

        const char* Ksb = Ks[cur];
        const char* Vsb = Vs[cur];

        f32x4 acc[8];
        #pragma unroll
        for (int mf = 0; mf < 8; mf++) acc[mf] = (f32x4){0.f, 0.f, 0.f, 0.f};
        #pragma unroll
        for (int kk = 0; kk < 2; kk++)
            #pragma unroll
            for (int mf = 0; mf < 8; mf++) {
                int row = mf * 16 + lrow;
                bf16x8 kf = *(const bf16x8*)(Ksb + row * 128 + (((kk * 4 + g) ^ (row & 7)) << 4));
                acc[mf] = MFMA16(kf, qf[kk], acc[mf]);
            }

        float s[8][4];
        float tmx = -1e30f;
        const bool lastT = (kt == ntiles - 1);
        #pragma unroll
        for (int mf = 0; mf < 8; mf++) {
            int kvb = kt * 128 + mf * 16 + g * 4;
            #pragma unroll
            for (int r = 0; r < 4; r++) {
                float sv = acc[mf][r] * c1;
                if (lastT) sv = (kvb + r <= qg) ? sv : -1e30f;
                s[mf][r] = sv;
                tmx = fmaxf(tmx, sv);
            }
        }
        if (!__all((int)(tmx <= m2 + 6.f))) {
            float tm = fmaxf(tmx, __shfl_xor(tmx, 16));
            tm = fmaxf(tm, __shfl_xor(tm, 32));
            float nm = fmaxf(m2, tm);
            float sc = exp2f(m2 - nm);
            l *= sc;
            #pragma unroll
            for (int md = 0; md < 4; md++) acc2[md] *= sc;
            m2 = nm;
        }
        float sum = 0.f;
        #pragma unroll
        for (int mf = 0; mf < 8; mf++) {
            float p0 = exp2f(s[mf][0] - m2);
            float p1 = exp2f(s[mf][1] - m2);
            float p2 = exp2f(s[mf][2] - m2);
            float p3 = exp2f(s[mf][3] - m2);
            sum += (p0 + p1) + (p2 + p3);
            uint2 pk;
            pk.x = pack_bf16x2(p0, p1);
            pk.y = pack_bf16x2(p2, p3);
            *(uint2*)(plB + ((lrow * 256 + mf * 32 + g * 8) ^ ((lrow & 7) << 4))) = pk;
        }
        l += sum;

        #pragma unroll
        for (int ks = 0; ks < 4; ks++) {
            bf16x8 pf = *(bf16x8*)(plB + ((lrow * 256 + ks * 64 + g * 16) ^ ((lrow & 7) << 4)));
            #pragma unroll
            for (int md = 0; md < 4; md++) {
                int row = md * 16 + lrow;
                bf16x8 vf = *(const bf16x8*)(Vsb + row * 256 + (((ks * 4 + g) ^ (row & 7)) << 4));
                acc2[md] = MFMA16(vf, pf, acc2[md]);
            }
        }
        __syncthreads();   // reads of buf[cur] done before it is restaged
    }

    l += __shfl_xor(l, 16);
    l += __shfl_xor(l, 32);
    float li = 1.f / l;
    if (lane < 16)
        Obuf[h * S_LEN + qg] = -m2 - log2f(l);
    #pragma unroll
    for (int md = 0; md < 4; md++) {
        uint2 pk;
        pk.x = pack_bf16x2(acc2[md][0] * li, acc2[md][1] * li);
        pk.y = pack_bf16x2(acc2[md][2] * li, acc2[md][3] * li);
        *(uint2*)(ctx + (size_t)qg * D_MOD + h * DK + md * 16 + g * 4) = pk;
    }
}

// ---------------------------------------------------------------------------
// ff1_pwrite: [0,512) ff1 GEMM; [512,1600) P tiles for heads [0,8)
// ---------------------------------------------------------------------------
__global__ __launch_bounds__(256)
void ff1_pwrite(const __bf16* __restrict__ A, const __bf16* __restrict__ BT,
                const float* __restrict__ bias, __bf16* __restrict__ Cb,
                const __bf16* __restrict__ qkv, const float* __restrict__ Obuf,
                float* __restrict__ P)
{
    __shared__ uint4 As[128 * 8];
    __shared__ uint4 Bs[128 * 8];
    if (blockIdx.x < 512) {
        int bid = blockIdx.x;
        gemm_dev<128, true, false, false, false, true, false>(
            A, BT, bias, nullptr, nullptr, nullptr, Cb, nullptr,
            D_FF, 1024, 1024, bid & 31, bid >> 5, As, Bs);
        return;
    }
    int idp = blockIdx.x - 512;      // [0,1088)
    int h = idp / 136;
    int tt = idp - h * 136;
    int qt = 0;
    while (tt > qt) { tt -= qt + 1; qt++; }
    pwrite_tile(qkv, Obuf, P, h, qt, tt);
}

// ---------------------------------------------------------------------------
// ff2_pwrite: [0,512) ff2 split-K halves; [512,1600) P tiles heads [8,16)
// ---------------------------------------------------------------------------
__global__ __launch_bounds__(256)
void ff2_pwrite(const __bf16* __restrict__ ff1_b, const __bf16* __restrict__ Wf2T,
                float* __restrict__ partA, float* __restrict__ partB,
                const __bf16* __restrict__ qkv, const float* __restrict__ Obuf,
                float* __restrict__ P)
{
    __shared__ uint4 As[128 * 8];
    __shared__ uint4 Bs[64 * 8];
    if (blockIdx.x < 512) {
        int half = blockIdx.x >> 8;
        int b2 = blockIdx.x & 255;
        const __bf16* Ah = ff1_b + half * 2048;
        const __bf16* Bh = Wf2T + half * 2048;
        float* Cf = half ? partB : partA;
        gemm_dev<64, false, false, false, true, false, false>(
            Ah, Bh, nullptr, nullptr, nullptr, Cf, nullptr, nullptr,
            1024, 4096, 2048, b2 & 15, b2 >> 4, As, Bs);
        return;
    }
    int idp = blockIdx.x - 512;      // [0,1088)
    int h = 8 + idp / 136;
    int tt = idp - (idp / 136) * 136;
    int qt = 0;
    while (tt > qt) { tt -= qt + 1; qt++; }
    pwrite_tile(qkv, Obuf, P, h, qt, tt);
}

// ---------------------------------------------------------------------------
// ff2_reduce: out = partA + partB + norm2 + bf2
// ---------------------------------------------------------------------------
__global__ __launch_bounds__(256)
void ff2_reduce(const float* __restrict__ partA, const float* __restrict__ partB,
                const float* __restrict__ norm2f, const float* __restrict__ bf2,
                float* __restrict__ outp)
{
    int idx = blockIdx.x * 256 + threadIdx.x;
    int col = (idx * 4) & 1023;
    f32x4 a = *(const f32x4*)(partA + (size_t)idx * 4);
    f32x4 b = *(const f32x4*)(partB + (size_t)idx * 4);
    f32x4 n = *(const f32x4*)(norm2f + (size_t)idx * 4);
    f32x4 bb = *(const f32x4*)(bf2 + col);
    f32x4 o = a + b + n + bb;
    *(f32x4*)(outp + (size_t)idx * 4) = o;
}

// ---------------------------------------------------------------------------
extern "C" void kernel_launch(void* const* d_in, const int* in_sizes, int n_in,
                              void* d_out, int out_size, void* d_ws, size_t ws_size,
                              hipStream_t stream)
{
    const float* x     = (const float*)d_in[0];
    const float* g1    = (const float*)d_in[1];
    const float* beta1 = (const float*)d_in[2];
    const float* W_in  = (const float*)d_in[3];
    const float* b_in  = (const float*)d_in[4];
    const float* Wq    = (const float*)d_in[5];
    const float* bq    = (const float*)d_in[6];
    const float* Wk    = (const float*)d_in[7];
    const float* bk    = (const float*)d_in[8];
    const float* Wv    = (const float*)d_in[9];
    const float* bv    = (const float*)d_in[10];
    const float* Wo    = (const float*)d_in[11];
    const float* bo    = (const float*)d_in[12];
    const float* W2    = (const float*)d_in[13];
    const float* b2    = (const float*)d_in[14];
    const float* g2    = (const float*)d_in[15];
    const float* beta2 = (const float*)d_in[16];
    const float* Wf1   = (const float*)d_in[17];
    const float* bf1   = (const float*)d_in[18];
    const float* Wf2   = (const float*)d_in[19];
    const float* bf2   = (const float*)d_in[20];

    float* outp = (float*)d_out;                    // [2048][1024]
    float* Pout = outp + (size_t)S_LEN * D_MOD;     // [16][2048][2048]

    char* p = (char*)d_ws;
    auto alloc = [&](size_t b) -> void* {
        void* r = (void*)p;
        p += (b + 255) & ~(size_t)255;
        return r;
    };
    __bf16* WqkvT    = (__bf16*)alloc((size_t)3072 * 1024 * 2);
    __bf16* W2T      = (__bf16*)alloc((size_t)1024 * 1024 * 2);
    __bf16* Wf1T     = (__bf16*)alloc((size_t)D_FF * D_MOD * 2);
    __bf16* Wf2T     = (__bf16*)alloc((size_t)D_MOD * D_FF * 2);
    __bf16* WqkvCT   = (__bf16*)alloc((size_t)3072 * 1024 * 2);
    __bf16* WcombT   = (__bf16*)alloc((size_t)1024 * 1024 * 2);
    float*  bqkv     = (float*)alloc((size_t)3072 * 4);
    float*  bcomb    = (float*)alloc((size_t)1024 * 4);
    float*  biaspart = (float*)alloc((size_t)8 * 4096 * 4);
    __bf16* xn_b     = (__bf16*)alloc((size_t)S_LEN * D_MOD * 2);
    __bf16* qkv_b    = (__bf16*)alloc((size_t)S_LEN * 3072 * 2);
    __bf16* VT       = (__bf16*)alloc((size_t)N_HEADS * DK * S_LEN * 2);
    __bf16* ctx_b    = (__bf16*)alloc((size_t)S_LEN * D_MOD * 2);
    float*  part1f   = (float*)alloc((size_t)S_LEN * D_MOD * 4);
    float*  norm2f   = (float*)alloc((size_t)S_LEN * D_MOD * 4);
    __bf16* norm2b   = (__bf16*)alloc((size_t)S_LEN * D_MOD * 2);
    __bf16* ff1_b    = (__bf16*)alloc((size_t)S_LEN * D_FF * 2);
    float*  Obuf     = (float*)alloc((size_t)N_HEADS * S_LEN * 4);
    float*  ffpartB  = (float*)alloc((size_t)S_LEN * D_MOD * 4);
    // aliases (lifetimes disjoint, stream-ordered):
    __bf16* Win_b   = (__bf16*)part1f;
    __bf16* Wo_b    = (__bf16*)norm2f;
    float*  ffpartA = part1f;

    dim3 blk(256);

    prep1<<<dim3(14464), blk, 0, stream>>>(Wq, Wk, Wv, W2, Wf1, Wf2, W_in, Wo,
                                           b_in, bo, WqkvT, W2T, Wf1T, Wf2T,
                                           Win_b, Wo_b, biaspart);

    prep2<<<dim3(2576), blk, 0, stream>>>(WqkvT, Win_b, WqkvCT, W2T, Wo_b, WcombT,
                                          biaspart, bq, bk, bv, b2, bqkv, bcomb,
                                          x, g1, beta1, xn_b);

    // qkv GEMM (+ fused VT transpose) + 960 P zero-fill backfill
    qkv_zf<<<dim3(384 + 960), blk, 0, stream>>>(xn_b, WqkvCT, bqkv, qkv_b, VT, Pout);

    // flash attention (dbuf prefetch) + remaining 960 zero-fill backfill
    attn_flash<<<dim3(512 + 960), blk, 0, stream>>>(qkv_b, VT, Obuf, ctx_b, Pout);

    gemm_kernel<64, false, true, false, true, false><<<dim3(16, 16), blk, 0, stream>>>(
        ctx_b, WcombT, bcomb, x, nullptr, part1f, nullptr, 1024, 1024, 1024);

    ln_kernel<<<S_LEN, blk, 0, stream>>>(part1f, g2, beta2, norm2b, norm2f);

    ff1_pwrite<<<dim3(512 + 1088), blk, 0, stream>>>(
        norm2b, Wf1T, bf1, ff1_b, qkv_b, Obuf, Pout);

    ff2_pwrite<<<dim3(512 + 1088), blk, 0, stream>>>(
        ff1_b, Wf2T, ffpartA, ffpartB, qkv_b, Obuf, Pout);

    ff2_reduce<<<dim3(2048), blk, 0, stream>>>(ffpartA, ffpartB, norm2f, bf2, outp);
}